// Round 19
// baseline (197.690 us; speedup 1.0000x reference)
//
#include <hip/hip_runtime.h>
#include <stdint.h>

#define NHEAD 16
#define SEQ 2048
#define BATCH 4
#define NT (SEQ / 64)   // 32 kv tiles of 64

typedef short short8 __attribute__((ext_vector_type(8)));     // 8 bf16 (4 VGPRs)
typedef _Float16 half8 __attribute__((ext_vector_type(8)));   // 8 fp16 (4 VGPRs)
typedef _Float16 half4 __attribute__((ext_vector_type(4)));   // 4 fp16 (8B)
typedef float f32x4  __attribute__((ext_vector_type(4)));     // MFMA accumulator
typedef __bf16 bf16x2 __attribute__((ext_vector_type(2)));

typedef const __attribute__((address_space(1))) void* gas_t;
typedef __attribute__((address_space(3))) void* las_t;
#define GLL16(g, s) __builtin_amdgcn_global_load_lds((gas_t)(g), (las_t)(s), 16, 0, 0)

static __device__ __forceinline__ unsigned short f2bfn(float f) {
    union { __bf16 b; unsigned short u; } cv;
    cv.b = (__bf16)f;
    return cv.u;
}
static __device__ __forceinline__ uint32_t pkbf(float a, float b) {
    union { bf16x2 v; uint32_t u; } cv;
    cv.v[0] = (__bf16)a; cv.v[1] = (__bf16)b;
    return cv.u;
}
static __device__ __forceinline__ float exp2_fast(float x) {
#if __has_builtin(__builtin_amdgcn_exp2f)
    return __builtin_amdgcn_exp2f(x);
#else
    float r; asm("v_exp_f32 %0, %1\n\ts_nop 0" : "=v"(r) : "v"(x)); return r;
#endif
}

// ---------------------------------------------------------------------------
// Merged fp32 -> fp16 conversion for x, w_qkv, w_proj (one launch).
// ---------------------------------------------------------------------------
__global__ __launch_bounds__(256)
void conv3(const float* __restrict__ x,  _Float16* __restrict__ Xf,
           const float* __restrict__ wq, _Float16* __restrict__ Wf,
           const float* __restrict__ wp, _Float16* __restrict__ Wpf) {
    const int bid = blockIdx.x;
    const float* src;
    _Float16* dst;
    int base;
    if (bid < 4096)      { src = x;  dst = Xf;  base = bid; }
    else if (bid < 5632) { src = wq; dst = Wf;  base = bid - 4096; }
    else                 { src = wp; dst = Wpf; base = bid - 5632; }
    const int idx = (base * 256 + threadIdx.x) * 8;
    float4 v0 = *(const float4*)(src + idx);
    float4 v1 = *(const float4*)(src + idx + 4);
    half8 h;
    h[0] = (_Float16)v0.x; h[1] = (_Float16)v0.y;
    h[2] = (_Float16)v0.z; h[3] = (_Float16)v0.w;
    h[4] = (_Float16)v1.x; h[5] = (_Float16)v1.y;
    h[6] = (_Float16)v1.z; h[7] = (_Float16)v1.w;
    *(half8*)(dst + idx) = h;
}

// ---------------------------------------------------------------------------
// fp16 MFMA GEMM (r17, unchanged): 128x128 tile, BK=32, 4 waves, 3-buffer
// depth-2 GLL16 pipeline, counted vmcnt(4), XCD grid, compile-time SWP.
// ---------------------------------------------------------------------------
template<int EPI, int SWP>
__global__ __launch_bounds__(256)
void gemm_h(const _Float16* __restrict__ Af, const _Float16* __restrict__ Bf,
            int K, int N, int nbx, int bnoff,
            float* __restrict__ outF, const float* __restrict__ bias,
            unsigned short* __restrict__ Qb, unsigned short* __restrict__ Kb,
            unsigned short* __restrict__ Vt) {
    __shared__ _Float16 lds[3][2][4096];   // [buf][A|B][128*32]

    const int tid = threadIdx.x;
    const int l = tid & 63, wv = tid >> 6;
    const int wr = wv >> 1, wc = wv & 1;
    const int c = l & 15, g = l >> 4;

    const int id = blockIdx.x;
    const int xcd = id & 7, s = id >> 3;
    const int bpx = (gridDim.x >> 3) / nbx;    // by-rows per XCD
    const int by = xcd * bpx + s / nbx, bx = s % nbx;
    const int bm = by * 128, bn = bnoff + bx * 128;

    size_t aoff[2], boff[2];
    int ldsoff[2];
    #pragma unroll
    for (int u = 0; u < 2; ++u) {
        const int i = u * 256 + tid;
        const int row = i >> 2;
        const int gg = (i & 3) ^ ((i >> 3) & 3);    // inverse swizzle on source
        aoff[u] = (size_t)(bm + row) * K + gg * 8;
        boff[u] = (size_t)(bn + row) * K + gg * 8;
        ldsoff[u] = (u * 256 + wv * 64) * 8;
    }

    int offA[4], offB[4];
    #pragma unroll
    for (int m = 0; m < 4; ++m) {
        const int row = wr * 64 + m * 16 + c;
        offA[m] = row * 32 + (g ^ ((row >> 1) & 3)) * 8;
    }
    #pragma unroll
    for (int n = 0; n < 4; ++n) {
        const int row = wc * 64 + n * 16 + c;
        offB[n] = row * 32 + (g ^ ((row >> 1) & 3)) * 8;
    }

    #define GSTAGE(buf, kk) do {                                   \
        _Pragma("unroll")                                          \
        for (int u = 0; u < 2; ++u) {                              \
            GLL16(Af + aoff[u] + (kk), &lds[buf][0][ldsoff[u]]);   \
            GLL16(Bf + boff[u] + (kk), &lds[buf][1][ldsoff[u]]);   \
        }                                                          \
    } while (0)

    f32x4 acc[4][4] = {};
    const int NK = K >> 5;

    GSTAGE(0, 0);
    GSTAGE(1, 32);
    asm volatile("s_waitcnt vmcnt(4)" ::: "memory");
    __builtin_amdgcn_s_barrier();
    __builtin_amdgcn_sched_barrier(0);

    for (int ks = 0; ks < NK; ++ks) {
        const int cur = ks % 3;
        if (ks + 2 < NK) GSTAGE((ks + 2) % 3, (ks + 2) * 32);

        half8 a[4], b[4];
        #pragma unroll
        for (int m = 0; m < 4; ++m) a[m] = *(const half8*)&lds[cur][0][offA[m]];
        #pragma unroll
        for (int n = 0; n < 4; ++n) b[n] = *(const half8*)&lds[cur][1][offB[n]];

        __builtin_amdgcn_s_setprio(1);
        #pragma unroll
        for (int m = 0; m < 4; ++m)
            #pragma unroll
            for (int n = 0; n < 4; ++n) {
                if constexpr (SWP)
                    acc[m][n] = __builtin_amdgcn_mfma_f32_16x16x32_f16(
                        b[n], a[m], acc[m][n], 0, 0, 0);
                else
                    acc[m][n] = __builtin_amdgcn_mfma_f32_16x16x32_f16(
                        a[m], b[n], acc[m][n], 0, 0, 0);
            }
        __builtin_amdgcn_s_setprio(0);

        if (ks + 1 < NK) {
            if (ks + 2 < NK) {
                asm volatile("s_waitcnt vmcnt(4)" ::: "memory");
            } else {
                asm volatile("s_waitcnt vmcnt(0)" ::: "memory");
            }
            __builtin_amdgcn_s_barrier();
            __builtin_amdgcn_sched_barrier(0);
        }
    }
    #undef GSTAGE

    if constexpr (EPI == 0) {
        const int colbase = bn + wc * 64;                   // 64-aligned
        const int which = colbase >> 10;
        const int h = (colbase >> 6) & 15;
        if constexpr (SWP) {
            // Q/K planes: rows = m*16+c, cols = n*16+4g+r -> ushort4 stores
            const float qs = 0.125f * 1.44269504088896340736f;
            unsigned short* plane = (which == 0) ? Qb : Kb;
            const float sc = (which == 0) ? qs : 1.0f;
            #pragma unroll
            for (int m = 0; m < 4; ++m) {
                const int t = bm + wr * 64 + m * 16 + c;
                const int bb = t >> 11, nl = t & 2047;
                unsigned short* rowp = plane +
                    ((size_t)(bb * NHEAD + h) * SEQ + nl) * 64;
                #pragma unroll
                for (int n = 0; n < 4; ++n) {
                    ushort4 o;
                    o.x = f2bfn(acc[m][n][0] * sc);
                    o.y = f2bfn(acc[m][n][1] * sc);
                    o.z = f2bfn(acc[m][n][2] * sc);
                    o.w = f2bfn(acc[m][n][3] * sc);
                    *(ushort4*)(rowp + n * 16 + 4 * g) = o;
                }
            }
        } else {
            // V plane: rows = m*16+4g+r (contiguous nl), cols = n*16+c = d
            #pragma unroll
            for (int m = 0; m < 4; ++m) {
                const int trow0 = bm + wr * 64 + m * 16 + 4 * g;
                const int bb = trow0 >> 11, nl0 = trow0 & 2047;
                #pragma unroll
                for (int n = 0; n < 4; ++n) {
                    const int d = n * 16 + c;
                    ushort4 o;
                    o.x = f2bfn(acc[m][n][0]);
                    o.y = f2bfn(acc[m][n][1]);
                    o.z = f2bfn(acc[m][n][2]);
                    o.w = f2bfn(acc[m][n][3]);
                    *(ushort4*)(Vt + ((size_t)(bb * NHEAD + h) * 64 + d) * SEQ + nl0) = o;
                }
            }
        }
    } else {
        // proj (SWP=1): rows = m*16+c, cols = n*16+4g+r -> float4 + bias
        #pragma unroll
        for (int m = 0; m < 4; ++m) {
            const int t = bm + wr * 64 + m * 16 + c;
            #pragma unroll
            for (int n = 0; n < 4; ++n) {
                const int col0 = bn + wc * 64 + n * 16 + 4 * g;
                float4 bv = *(const float4*)&bias[col0];
                float4 o;
                o.x = acc[m][n][0] + bv.x;
                o.y = acc[m][n][1] + bv.y;
                o.z = acc[m][n][2] + bv.z;
                o.w = acc[m][n][3] + bv.w;
                *(float4*)&outF[(size_t)t * N + col0] = o;
            }
        }
    }
}

// ---------------------------------------------------------------------------
// MFMA flash attention — r17 per-wave code, 4-WAVE BLOCKS this round.
// 256 threads, 128 q-rows/block, 1024 blocks. LDS = 32KB (K/V dbuf only)
// -> 5 blocks/CU = 20 waves/CU (was 16) and 4-wave barrier groups (was 8):
// more independent wave-groups per CU to overlap QK/SM/PV across pipes.
// K/V staging per block unchanged (2 chunks/thread/plane); per-XCD L2
// working set unchanged (4MB) so the doubled stage traffic is L2-absorbed.
// Per-wave math identical to r17 (tau' in-register P, swapped PV).
// ---------------------------------------------------------------------------
__global__ __launch_bounds__(256)
void attn_mfma(const unsigned short* __restrict__ Qb, const unsigned short* __restrict__ Kb,
               const unsigned short* __restrict__ Vt, _Float16* __restrict__ Of) {
    __shared__ unsigned short Kl[2][4096];   // [64 row][64 d] swizzled, rows = tau'-permuted kv
    __shared__ unsigned short Vl[2][4096];   // [64 d][64 kv] swizzled, natural kv

    const int tid = threadIdx.x;
    const int l = tid & 63, w = tid >> 6;    // w = 0..3
    const int g = l >> 4, c = l & 15;
    const int sw = (c & 7) << 4;

    // 1024 blocks = 8 xcd x 8 bh x 16 q-panels of 128 rows
    const int blk = blockIdx.x;
    const int xcd = blk & 7, s0 = blk >> 3;        // s0 = 0..127
    const int bh = xcd * 8 + (s0 >> 4);
    const int b = bh >> 4, h = bh & 15;
    const int q0 = (s0 & 15) * 128;

    const unsigned short* QbBH = Qb + (size_t)bh * SEQ * 64;
    const unsigned short* KbBH = Kb + (size_t)bh * SEQ * 64;
    const unsigned short* VtBH = Vt + (size_t)bh * 64 * SEQ;

    // staging: 256 threads x 2 chunks x 16B per plane = 8KB tile
    const int i0 = tid, i1 = tid + 256;
    const int r0 = i0 >> 3, r1 = i1 >> 3;
    const int tau0 = (r0 & 32) | ((r0 & 12) << 1) | ((r0 & 16) >> 2) | (r0 & 3);
    const int tau1 = (r1 & 32) | ((r1 & 12) << 1) | ((r1 & 16) >> 2) | (r1 & 3);
    const unsigned short* sK0 = KbBH + (size_t)tau0 * 64 + ((i0 & 7) ^ (r0 & 7)) * 8;
    const unsigned short* sK1 = KbBH + (size_t)tau1 * 64 + ((i1 & 7) ^ (r1 & 7)) * 8;
    const unsigned short* sV0 = VtBH + (size_t)r0 * SEQ + ((i0 & 7) ^ (r0 & 7)) * 8;
    const unsigned short* sV1 = VtBH + (size_t)r1 * SEQ + ((i1 & 7) ^ (r1 & 7)) * 8;

    #define STAGE(nb, tt) do {                                        \
        GLL16(sK0 + (size_t)(tt) * 4096, (char*)Kl[nb] + i0 * 16);    \
        GLL16(sK1 + (size_t)(tt) * 4096, (char*)Kl[nb] + i1 * 16);    \
        GLL16(sV0 + (tt) * 64,           (char*)Vl[nb] + i0 * 16);    \
        GLL16(sV1 + (tt) * 64,           (char*)Vl[nb] + i1 * 16);    \
    } while (0)

    int rdoff[2][4];   // [s][f]: K rows f*16+c / V rows df*16+c
    #pragma unroll
    for (int s = 0; s < 2; ++s)
        #pragma unroll
        for (int f = 0; f < 4; ++f)
            rdoff[s][f] = (f * 16 + c) * 128 + ((g * 16 + s * 64) ^ sw);

    short8 qf[2][2];
    #pragma unroll
    for (int m = 0; m < 2; ++m)
        #pragma unroll
        for (int s = 0; s < 2; ++s)
            qf[m][s] = *(const short8*)(QbBH +
                         (size_t)(q0 + w * 32 + m * 16 + c) * 64 + s * 32 + g * 8);

    f32x4 oacc[2][4] = {};
    float l_run[2] = {0.f, 0.f};

    STAGE(0, 0);
    __syncthreads();

    #define BODY(cur, tt, PF)                                                  \
    {                                                                          \
        if (PF) STAGE(cur ^ 1, (tt) + 1);                                      \
        f32x4 st[2][4] = {};                                                   \
        _Pragma("unroll")                                                      \
        for (int s = 0; s < 2; ++s) {                                          \
            short8 kf[4];                                                      \
            _Pragma("unroll")                                                  \
            for (int f = 0; f < 4; ++f)                                        \
                kf[f] = *(const short8*)((char*)Kl[cur] + rdoff[s][f]);        \
            __builtin_amdgcn_s_setprio(1);                                     \
            _Pragma("unroll")                                                  \
            for (int m = 0; m < 2; ++m)                                        \
                _Pragma("unroll")                                              \
                for (int f = 0; f < 4; ++f)                                    \
                    st[m][f] = __builtin_amdgcn_mfma_f32_16x16x32_bf16(        \
                        kf[f], qf[m][s], st[m][f], 0, 0, 0);                   \
            __builtin_amdgcn_s_setprio(0);                                     \
        }                                                                      \
        short8 pa[2][2];                                                       \
        _Pragma("unroll")                                                      \
        for (int m = 0; m < 2; ++m) {                                          \
            float p[4][4];                                                     \
            _Pragma("unroll")                                                  \
            for (int f = 0; f < 4; ++f)                                        \
                _Pragma("unroll")                                              \
                for (int r = 0; r < 4; ++r)                                    \
                    p[f][r] = exp2_fast(st[m][f][r]);                          \
            float rs = 0.f;                                                    \
            _Pragma("unroll")                                                  \
            for (int f = 0; f < 4; ++f)                                        \
                rs += (p[f][0] + p[f][1]) + (p[f][2] + p[f][3]);               \
            l_run[m] += rs;                                                    \
            uint4 u0, u1;                                                      \
            u0.x = pkbf(p[0][0], p[0][1]); u0.y = pkbf(p[0][2], p[0][3]);      \
            u0.z = pkbf(p[1][0], p[1][1]); u0.w = pkbf(p[1][2], p[1][3]);      \
            u1.x = pkbf(p[2][0], p[2][1]); u1.y = pkbf(p[2][2], p[2][3]);      \
            u1.z = pkbf(p[3][0], p[3][1]); u1.w = pkbf(p[3][2], p[3][3]);      \
            pa[m][0] = *(short8*)&u0;                                          \
            pa[m][1] = *(short8*)&u1;                                          \
        }                                                                      \
        _Pragma("unroll")                                                      \
        for (int s = 0; s < 2; ++s) {                                          \
            short8 vb[4];                                                      \
            _Pragma("unroll")                                                  \
            for (int df = 0; df < 4; ++df)                                     \
                vb[df] = *(const short8*)((char*)Vl[cur] + rdoff[s][df]);      \
            __builtin_amdgcn_s_setprio(1);                                     \
            _Pragma("unroll")                                                  \
            for (int m = 0; m < 2; ++m)                                        \
                _Pragma("unroll")                                              \
                for (int df = 0; df < 4; ++df)                                 \
                    oacc[m][df] = __builtin_amdgcn_mfma_f32_16x16x32_bf16(     \
                        vb[df], pa[m][s], oacc[m][df], 0, 0, 0);               \
            __builtin_amdgcn_s_setprio(0);                                     \
        }                                                                      \
        __syncthreads();                                                       \
    }

    for (int t = 0; t < NT; t += 2) {
        BODY(0, t, true);
        BODY(1, t + 1, (t + 2 < NT));
    }
    #undef BODY
    #undef STAGE

    // ---- epilogue: lane's own l (q = c); half4 stores over consecutive d ----
    #pragma unroll
    for (int m = 0; m < 2; ++m) {
        l_run[m] += __shfl_xor(l_run[m], 16);
        l_run[m] += __shfl_xor(l_run[m], 32);
        const float iv = __builtin_amdgcn_rcpf(l_run[m]);
        const size_t t = (size_t)(b * SEQ + q0 + w * 32 + m * 16 + c);
        _Float16* orow = Of + t * 1024 + h * 64;
        #pragma unroll
        for (int df = 0; df < 4; ++df) {
            half4 o;
            o[0] = (_Float16)(oacc[m][df][0] * iv);
            o[1] = (_Float16)(oacc[m][df][1] * iv);
            o[2] = (_Float16)(oacc[m][df][2] * iv);
            o[3] = (_Float16)(oacc[m][df][3] * iv);
            *(half4*)(orow + df * 16 + 4 * g) = o;
        }
    }
}

// ---------------------------------------------------------------------------
extern "C" void kernel_launch(void* const* d_in, const int* in_sizes, int n_in,
                              void* d_out, int out_size, void* d_ws, size_t ws_size,
                              hipStream_t stream) {
    const float* x      = (const float*)d_in[0];
    const float* w_qkv  = (const float*)d_in[1];
    const float* w_proj = (const float*)d_in[2];
    const float* b_proj = (const float*)d_in[3];
    float* out = (float*)d_out;

    char* ws = (char*)d_ws;
    const size_t MB = 1024 * 1024;
    _Float16* Xf  = (_Float16*)(ws);             // 16 MB
    _Float16* Of  = Xf;                          // alias: X dead after qkv GEMM
    _Float16* Wf  = (_Float16*)(ws + 16 * MB);   // 6 MB
    _Float16* Wpf = (_Float16*)(ws + 22 * MB);   // 2 MB
    unsigned short* Qb = (unsigned short*)(ws + 24 * MB);  // 16 MB
    unsigned short* Kb = (unsigned short*)(ws + 40 * MB);  // 16 MB
    unsigned short* Vt = (unsigned short*)(ws + 56 * MB);  // 16 MB -> 72 MB total

    // 1) fp16 conversions (single launch)
    conv3<<<6144, 256, 0, stream>>>(x, Xf, w_qkv, Wf, w_proj, Wpf);

    // 2a) qkv GEMM, Q/K columns (swapped, ushort4 epilogue)
    gemm_h<0, 1><<<1024, 256, 0, stream>>>(
        Xf, Wf, 1024, 3072, 16, 0, nullptr, nullptr, Qb, Kb, Vt);
    // 2b) qkv GEMM, V columns (unswapped, ushort4-over-nl epilogue)
    gemm_h<0, 0><<<512, 256, 0, stream>>>(
        Xf, Wf, 1024, 3072, 8, 2048, nullptr, nullptr, Qb, Kb, Vt);

    // 3) flash attention (4-wave blocks, 5 blk/CU, in-register P) -> Of
    attn_mfma<<<1024, 256, 0, stream>>>(Qb, Kb, Vt, Of);

    // 4) proj GEMM (float4 epilogue) + bias -> out
    gemm_h<1, 1><<<512, 256, 0, stream>>>(
        Of, Wpf, 1024, 1024, 8, 0, out, b_proj, nullptr, nullptr, nullptr);
}

// Round 20
// 191.743 us; speedup vs baseline: 1.0310x; 1.0310x over previous
//
#include <hip/hip_runtime.h>
#include <stdint.h>

#define NHEAD 16
#define SEQ 2048
#define BATCH 4
#define NT (SEQ / 64)   // 32 kv tiles of 64

typedef short short8 __attribute__((ext_vector_type(8)));     // 8 bf16 (4 VGPRs)
typedef _Float16 half8 __attribute__((ext_vector_type(8)));   // 8 fp16 (4 VGPRs)
typedef _Float16 half4 __attribute__((ext_vector_type(4)));   // 4 fp16 (8B)
typedef float f32x4  __attribute__((ext_vector_type(4)));     // MFMA accumulator
typedef __bf16 bf16x2 __attribute__((ext_vector_type(2)));

typedef const __attribute__((address_space(1))) void* gas_t;
typedef __attribute__((address_space(3))) void* las_t;
#define GLL16(g, s) __builtin_amdgcn_global_load_lds((gas_t)(g), (las_t)(s), 16, 0, 0)

static __device__ __forceinline__ unsigned short f2bfn(float f) {
    union { __bf16 b; unsigned short u; } cv;
    cv.b = (__bf16)f;
    return cv.u;
}
static __device__ __forceinline__ uint32_t pkbf(float a, float b) {
    union { bf16x2 v; uint32_t u; } cv;
    cv.v[0] = (__bf16)a; cv.v[1] = (__bf16)b;
    return cv.u;
}
static __device__ __forceinline__ float exp2_fast(float x) {
#if __has_builtin(__builtin_amdgcn_exp2f)
    return __builtin_amdgcn_exp2f(x);
#else
    float r; asm("v_exp_f32 %0, %1\n\ts_nop 0" : "=v"(r) : "v"(x)); return r;
#endif
}

// ---------------------------------------------------------------------------
// Merged fp32 -> fp16 conversion for x, w_qkv, w_proj (one launch).
// ---------------------------------------------------------------------------
__global__ __launch_bounds__(256)
void conv3(const float* __restrict__ x,  _Float16* __restrict__ Xf,
           const float* __restrict__ wq, _Float16* __restrict__ Wf,
           const float* __restrict__ wp, _Float16* __restrict__ Wpf) {
    const int bid = blockIdx.x;
    const float* src;
    _Float16* dst;
    int base;
    if (bid < 4096)      { src = x;  dst = Xf;  base = bid; }
    else if (bid < 5632) { src = wq; dst = Wf;  base = bid - 4096; }
    else                 { src = wp; dst = Wpf; base = bid - 5632; }
    const int idx = (base * 256 + threadIdx.x) * 8;
    float4 v0 = *(const float4*)(src + idx);
    float4 v1 = *(const float4*)(src + idx + 4);
    half8 h;
    h[0] = (_Float16)v0.x; h[1] = (_Float16)v0.y;
    h[2] = (_Float16)v0.z; h[3] = (_Float16)v0.w;
    h[4] = (_Float16)v1.x; h[5] = (_Float16)v1.y;
    h[6] = (_Float16)v1.z; h[7] = (_Float16)v1.w;
    *(half8*)(dst + idx) = h;
}

// ---------------------------------------------------------------------------
// fp16 MFMA GEMM (r17, unchanged): 128x128 tile, BK=32, 4 waves, 3-buffer
// depth-2 GLL16 pipeline, counted vmcnt(4), XCD grid, compile-time SWP.
// ---------------------------------------------------------------------------
template<int EPI, int SWP>
__global__ __launch_bounds__(256)
void gemm_h(const _Float16* __restrict__ Af, const _Float16* __restrict__ Bf,
            int K, int N, int nbx, int bnoff,
            float* __restrict__ outF, const float* __restrict__ bias,
            unsigned short* __restrict__ Qb, unsigned short* __restrict__ Kb,
            unsigned short* __restrict__ Vt) {
    __shared__ _Float16 lds[3][2][4096];   // [buf][A|B][128*32]

    const int tid = threadIdx.x;
    const int l = tid & 63, wv = tid >> 6;
    const int wr = wv >> 1, wc = wv & 1;
    const int c = l & 15, g = l >> 4;

    const int id = blockIdx.x;
    const int xcd = id & 7, s = id >> 3;
    const int bpx = (gridDim.x >> 3) / nbx;    // by-rows per XCD
    const int by = xcd * bpx + s / nbx, bx = s % nbx;
    const int bm = by * 128, bn = bnoff + bx * 128;

    size_t aoff[2], boff[2];
    int ldsoff[2];
    #pragma unroll
    for (int u = 0; u < 2; ++u) {
        const int i = u * 256 + tid;
        const int row = i >> 2;
        const int gg = (i & 3) ^ ((i >> 3) & 3);    // inverse swizzle on source
        aoff[u] = (size_t)(bm + row) * K + gg * 8;
        boff[u] = (size_t)(bn + row) * K + gg * 8;
        ldsoff[u] = (u * 256 + wv * 64) * 8;
    }

    int offA[4], offB[4];
    #pragma unroll
    for (int m = 0; m < 4; ++m) {
        const int row = wr * 64 + m * 16 + c;
        offA[m] = row * 32 + (g ^ ((row >> 1) & 3)) * 8;
    }
    #pragma unroll
    for (int n = 0; n < 4; ++n) {
        const int row = wc * 64 + n * 16 + c;
        offB[n] = row * 32 + (g ^ ((row >> 1) & 3)) * 8;
    }

    #define GSTAGE(buf, kk) do {                                   \
        _Pragma("unroll")                                          \
        for (int u = 0; u < 2; ++u) {                              \
            GLL16(Af + aoff[u] + (kk), &lds[buf][0][ldsoff[u]]);   \
            GLL16(Bf + boff[u] + (kk), &lds[buf][1][ldsoff[u]]);   \
        }                                                          \
    } while (0)

    f32x4 acc[4][4] = {};
    const int NK = K >> 5;

    GSTAGE(0, 0);
    GSTAGE(1, 32);
    asm volatile("s_waitcnt vmcnt(4)" ::: "memory");
    __builtin_amdgcn_s_barrier();
    __builtin_amdgcn_sched_barrier(0);

    for (int ks = 0; ks < NK; ++ks) {
        const int cur = ks % 3;
        if (ks + 2 < NK) GSTAGE((ks + 2) % 3, (ks + 2) * 32);

        half8 a[4], b[4];
        #pragma unroll
        for (int m = 0; m < 4; ++m) a[m] = *(const half8*)&lds[cur][0][offA[m]];
        #pragma unroll
        for (int n = 0; n < 4; ++n) b[n] = *(const half8*)&lds[cur][1][offB[n]];

        __builtin_amdgcn_s_setprio(1);
        #pragma unroll
        for (int m = 0; m < 4; ++m)
            #pragma unroll
            for (int n = 0; n < 4; ++n) {
                if constexpr (SWP)
                    acc[m][n] = __builtin_amdgcn_mfma_f32_16x16x32_f16(
                        b[n], a[m], acc[m][n], 0, 0, 0);
                else
                    acc[m][n] = __builtin_amdgcn_mfma_f32_16x16x32_f16(
                        a[m], b[n], acc[m][n], 0, 0, 0);
            }
        __builtin_amdgcn_s_setprio(0);

        if (ks + 1 < NK) {
            if (ks + 2 < NK) {
                asm volatile("s_waitcnt vmcnt(4)" ::: "memory");
            } else {
                asm volatile("s_waitcnt vmcnt(0)" ::: "memory");
            }
            __builtin_amdgcn_s_barrier();
            __builtin_amdgcn_sched_barrier(0);
        }
    }
    #undef GSTAGE

    if constexpr (EPI == 0) {
        const int colbase = bn + wc * 64;                   // 64-aligned
        const int which = colbase >> 10;
        const int h = (colbase >> 6) & 15;
        if constexpr (SWP) {
            // Q/K planes: rows = m*16+c, cols = n*16+4g+r -> ushort4 stores
            const float qs = 0.125f * 1.44269504088896340736f;
            unsigned short* plane = (which == 0) ? Qb : Kb;
            const float sc = (which == 0) ? qs : 1.0f;
            #pragma unroll
            for (int m = 0; m < 4; ++m) {
                const int t = bm + wr * 64 + m * 16 + c;
                const int bb = t >> 11, nl = t & 2047;
                unsigned short* rowp = plane +
                    ((size_t)(bb * NHEAD + h) * SEQ + nl) * 64;
                #pragma unroll
                for (int n = 0; n < 4; ++n) {
                    ushort4 o;
                    o.x = f2bfn(acc[m][n][0] * sc);
                    o.y = f2bfn(acc[m][n][1] * sc);
                    o.z = f2bfn(acc[m][n][2] * sc);
                    o.w = f2bfn(acc[m][n][3] * sc);
                    *(ushort4*)(rowp + n * 16 + 4 * g) = o;
                }
            }
        } else {
            // V plane: rows = m*16+4g+r (contiguous nl), cols = n*16+c = d
            #pragma unroll
            for (int m = 0; m < 4; ++m) {
                const int trow0 = bm + wr * 64 + m * 16 + 4 * g;
                const int bb = trow0 >> 11, nl0 = trow0 & 2047;
                #pragma unroll
                for (int n = 0; n < 4; ++n) {
                    const int d = n * 16 + c;
                    ushort4 o;
                    o.x = f2bfn(acc[m][n][0]);
                    o.y = f2bfn(acc[m][n][1]);
                    o.z = f2bfn(acc[m][n][2]);
                    o.w = f2bfn(acc[m][n][3]);
                    *(ushort4*)(Vt + ((size_t)(bb * NHEAD + h) * 64 + d) * SEQ + nl0) = o;
                }
            }
        }
    } else {
        // proj (SWP=1): rows = m*16+c, cols = n*16+4g+r -> float4 + bias
        #pragma unroll
        for (int m = 0; m < 4; ++m) {
            const int t = bm + wr * 64 + m * 16 + c;
            #pragma unroll
            for (int n = 0; n < 4; ++n) {
                const int col0 = bn + wc * 64 + n * 16 + 4 * g;
                float4 bv = *(const float4*)&bias[col0];
                float4 o;
                o.x = acc[m][n][0] + bv.x;
                o.y = acc[m][n][1] + bv.y;
                o.z = acc[m][n][2] + bv.z;
                o.w = acc[m][n][3] + bv.w;
                *(float4*)&outF[(size_t)t * N + col0] = o;
            }
        }
    }
}

// ---------------------------------------------------------------------------
// MFMA flash attention — r17 per-wave code + COUNTED-VMCNT 4-BUFFER pipeline.
// 512 thr, 256 q-rows, grid 512 (2 blk/CU). Per tile: vmcnt(8) [oldest 4
// loads = this tile's K/V landed] -> raw s_barrier [all waves' loads landed;
// also separates STAGE(t+3) from last read of buf (t+3)%4 at tile t-1] ->
// STAGE(t+3) -> compute. No vmcnt(0) drain (r17's __syncthreads drained the
// just-issued prefetch every tile = m97 structural stall). Tail: vmcnt(4)/(0).
// LDS 4x(8K+8K) = 64KB. Per-wave math byte-identical to r17.
// ---------------------------------------------------------------------------
__global__ __launch_bounds__(512)
void attn_mfma(const unsigned short* __restrict__ Qb, const unsigned short* __restrict__ Kb,
               const unsigned short* __restrict__ Vt, _Float16* __restrict__ Of) {
    __shared__ unsigned short Kl[4][4096];   // [buf][64 row][64 d], rows = tau'-permuted kv
    __shared__ unsigned short Vl[4][4096];   // [buf][64 d][64 kv], natural kv

    const int tid = threadIdx.x;
    const int l = tid & 63, w = tid >> 6;
    const int g = l >> 4, c = l & 15;
    const int sw = (c & 7) << 4;

    const int blk = blockIdx.x;
    const int xcd = blk & 7, s0 = blk >> 3;
    const int bh = xcd * 8 + (s0 >> 3);
    const int b = bh >> 4, h = bh & 15;
    const int q0 = (s0 & 7) * 256;

    const unsigned short* QbBH = Qb + (size_t)bh * SEQ * 64;
    const unsigned short* KbBH = Kb + (size_t)bh * SEQ * 64;
    const unsigned short* VtBH = Vt + (size_t)bh * 64 * SEQ;

    const int r0 = tid >> 3;
    const int tau0 = (r0 & 32) | ((r0 & 12) << 1) | ((r0 & 16) >> 2) | (r0 & 3);
    const unsigned short* sK0 = KbBH + (size_t)tau0 * 64 + ((tid & 7) ^ (r0 & 7)) * 8;
    const unsigned short* sV0 = VtBH + (size_t)r0 * SEQ + ((tid & 7) ^ (r0 & 7)) * 8;

    // one tile = 4 GLL16s per wave-slot (512 thr x 16B = 8KB per plane)
    #define STAGE(nb, tt) do {                                        \
        GLL16(sK0 + (size_t)(tt) * 4096, (char*)Kl[nb] + tid * 16);   \
        GLL16(sV0 + (tt) * 64,           (char*)Vl[nb] + tid * 16);   \
    } while (0)

    int rdoff[2][4];   // [s][f]: K rows f*16+c / V rows df*16+c
    #pragma unroll
    for (int s = 0; s < 2; ++s)
        #pragma unroll
        for (int f = 0; f < 4; ++f)
            rdoff[s][f] = (f * 16 + c) * 128 + ((g * 16 + s * 64) ^ sw);

    short8 qf[2][2];
    #pragma unroll
    for (int m = 0; m < 2; ++m)
        #pragma unroll
        for (int s = 0; s < 2; ++s)
            qf[m][s] = *(const short8*)(QbBH +
                         (size_t)(q0 + w * 32 + m * 16 + c) * 64 + s * 32 + g * 8);

    f32x4 oacc[2][4] = {};
    float l_run[2] = {0.f, 0.f};

    // prologue: stage tiles 0,1,2 (12 loads in flight; 2/STAGE here = 6? no:
    // STAGE = 2 GLL16s (K+V). Queue counts: 2 loads per tile per wave-slot.
    STAGE(0, 0); STAGE(1, 1); STAGE(2, 2);   // 6 outstanding / thread-slot

    // Per tile: wait oldest 2 (this tile's K+V) => vmcnt(4) [tiles t+1,t+2
    // in flight = 4]; barrier; stage t+3 (+2 -> 6); compute. Tail: vmcnt(2)/(0).
    #define BODY(buf, tt, PF, VMW)                                             \
    {                                                                          \
        asm volatile("s_waitcnt vmcnt(" #VMW ")" ::: "memory");                \
        __builtin_amdgcn_s_barrier();                                          \
        __builtin_amdgcn_sched_barrier(0);                                     \
        if (PF) STAGE((buf + 3) & 3, (tt) + 3);                                \
        f32x4 st[2][4] = {};                                                   \
        _Pragma("unroll")                                                      \
        for (int s = 0; s < 2; ++s) {                                          \
            short8 kf[4];                                                      \
            _Pragma("unroll")                                                  \
            for (int f = 0; f < 4; ++f)                                        \
                kf[f] = *(const short8*)((char*)Kl[buf] + rdoff[s][f]);        \
            __builtin_amdgcn_s_setprio(1);                                     \
            _Pragma("unroll")                                                  \
            for (int m = 0; m < 2; ++m)                                        \
                _Pragma("unroll")                                              \
                for (int f = 0; f < 4; ++f)                                    \
                    st[m][f] = __builtin_amdgcn_mfma_f32_16x16x32_bf16(        \
                        kf[f], qf[m][s], st[m][f], 0, 0, 0);                   \
            __builtin_amdgcn_s_setprio(0);                                     \
        }                                                                      \
        short8 pa[2][2];                                                       \
        _Pragma("unroll")                                                      \
        for (int m = 0; m < 2; ++m) {                                          \
            float p[4][4];                                                     \
            _Pragma("unroll")                                                  \
            for (int f = 0; f < 4; ++f)                                        \
                _Pragma("unroll")                                              \
                for (int r = 0; r < 4; ++r)                                    \
                    p[f][r] = exp2_fast(st[m][f][r]);                          \
            float rs = 0.f;                                                    \
            _Pragma("unroll")                                                  \
            for (int f = 0; f < 4; ++f)                                        \
                rs += (p[f][0] + p[f][1]) + (p[f][2] + p[f][3]);               \
            l_run[m] += rs;                                                    \
            uint4 u0, u1;                                                      \
            u0.x = pkbf(p[0][0], p[0][1]); u0.y = pkbf(p[0][2], p[0][3]);      \
            u0.z = pkbf(p[1][0], p[1][1]); u0.w = pkbf(p[1][2], p[1][3]);      \
            u1.x = pkbf(p[2][0], p[2][1]); u1.y = pkbf(p[2][2], p[2][3]);      \
            u1.z = pkbf(p[3][0], p[3][1]); u1.w = pkbf(p[3][2], p[3][3]);      \
            pa[m][0] = *(short8*)&u0;                                          \
            pa[m][1] = *(short8*)&u1;                                          \
        }                                                                      \
        _Pragma("unroll")                                                      \
        for (int s = 0; s < 2; ++s) {                                          \
            short8 vb[4];                                                      \
            _Pragma("unroll")                                                  \
            for (int df = 0; df < 4; ++df)                                     \
                vb[df] = *(const short8*)((char*)Vl[buf] + rdoff[s][df]);      \
            __builtin_amdgcn_s_setprio(1);                                     \
            _Pragma("unroll")                                                  \
            for (int m = 0; m < 2; ++m)                                        \
                _Pragma("unroll")                                              \
                for (int df = 0; df < 4; ++df)                                 \
                    oacc[m][df] = __builtin_amdgcn_mfma_f32_16x16x32_bf16(     \
                        vb[df], pa[m][s], oacc[m][df], 0, 0, 0);               \
            __builtin_amdgcn_s_setprio(0);                                     \
        }                                                                      \
    }

    for (int t = 0; t < NT - 4; t += 4) {
        BODY(0, t,     true, 4);
        BODY(1, t + 1, true, 4);
        BODY(2, t + 2, true, 4);
        BODY(3, t + 3, true, 4);
    }
    BODY(0, NT - 4, true,  4);    // stages tile NT-1
    BODY(1, NT - 3, false, 4);
    BODY(2, NT - 2, false, 2);
    BODY(3, NT - 1, false, 0);
    #undef BODY
    #undef STAGE

    // ---- epilogue: lane's own l (q = c); half4 stores over consecutive d ----
    #pragma unroll
    for (int m = 0; m < 2; ++m) {
        l_run[m] += __shfl_xor(l_run[m], 16);
        l_run[m] += __shfl_xor(l_run[m], 32);
        const float iv = __builtin_amdgcn_rcpf(l_run[m]);
        const size_t t = (size_t)(b * SEQ + q0 + w * 32 + m * 16 + c);
        _Float16* orow = Of + t * 1024 + h * 64;
        #pragma unroll
        for (int df = 0; df < 4; ++df) {
            half4 o;
            o[0] = (_Float16)(oacc[m][df][0] * iv);
            o[1] = (_Float16)(oacc[m][df][1] * iv);
            o[2] = (_Float16)(oacc[m][df][2] * iv);
            o[3] = (_Float16)(oacc[m][df][3] * iv);
            *(half4*)(orow + df * 16 + 4 * g) = o;
        }
    }
}

// ---------------------------------------------------------------------------
extern "C" void kernel_launch(void* const* d_in, const int* in_sizes, int n_in,
                              void* d_out, int out_size, void* d_ws, size_t ws_size,
                              hipStream_t stream) {
    const float* x      = (const float*)d_in[0];
    const float* w_qkv  = (const float*)d_in[1];
    const float* w_proj = (const float*)d_in[2];
    const float* b_proj = (const float*)d_in[3];
    float* out = (float*)d_out;

    char* ws = (char*)d_ws;
    const size_t MB = 1024 * 1024;
    _Float16* Xf  = (_Float16*)(ws);             // 16 MB
    _Float16* Of  = Xf;                          // alias: X dead after qkv GEMM
    _Float16* Wf  = (_Float16*)(ws + 16 * MB);   // 6 MB
    _Float16* Wpf = (_Float16*)(ws + 22 * MB);   // 2 MB
    unsigned short* Qb = (unsigned short*)(ws + 24 * MB);  // 16 MB
    unsigned short* Kb = (unsigned short*)(ws + 40 * MB);  // 16 MB
    unsigned short* Vt = (unsigned short*)(ws + 56 * MB);  // 16 MB -> 72 MB total

    // 1) fp16 conversions (single launch)
    conv3<<<6144, 256, 0, stream>>>(x, Xf, w_qkv, Wf, w_proj, Wpf);

    // 2a) qkv GEMM, Q/K columns (swapped, ushort4 epilogue)
    gemm_h<0, 1><<<1024, 256, 0, stream>>>(
        Xf, Wf, 1024, 3072, 16, 0, nullptr, nullptr, Qb, Kb, Vt);
    // 2b) qkv GEMM, V columns (unswapped, ushort4-over-nl epilogue)
    gemm_h<0, 0><<<512, 256, 0, stream>>>(
        Xf, Wf, 1024, 3072, 8, 2048, nullptr, nullptr, Qb, Kb, Vt);

    // 3) flash attention (counted-vmcnt 4-buffer pipeline) -> Of
    attn_mfma<<<512, 512, 0, stream>>>(Qb, Kb, Vt, Of);

    // 4) proj GEMM (float4 epilogue) + bias -> out
    gemm_h<1, 1><<<512, 256, 0, stream>>>(
        Of, Wpf, 1024, 1024, 8, 0, out, b_proj, nullptr, nullptr, nullptr);
}

// Round 21
// 180.700 us; speedup vs baseline: 1.0940x; 1.0611x over previous
//
#include <hip/hip_runtime.h>
#include <stdint.h>

#define NHEAD 16
#define SEQ 2048
#define BATCH 4
#define NT (SEQ / 64)   // 32 kv tiles of 64

typedef short short8 __attribute__((ext_vector_type(8)));     // 8 bf16 (4 VGPRs)
typedef _Float16 half8 __attribute__((ext_vector_type(8)));   // 8 fp16 (4 VGPRs)
typedef _Float16 half4 __attribute__((ext_vector_type(4)));   // 4 fp16 (8B)
typedef float f32x4  __attribute__((ext_vector_type(4)));     // MFMA accumulator
typedef __bf16 bf16x2 __attribute__((ext_vector_type(2)));

typedef const __attribute__((address_space(1))) void* gas_t;
typedef __attribute__((address_space(3))) void* las_t;
#define GLL16(g, s) __builtin_amdgcn_global_load_lds((gas_t)(g), (las_t)(s), 16, 0, 0)

static __device__ __forceinline__ unsigned short f2bfn(float f) {
    union { __bf16 b; unsigned short u; } cv;
    cv.b = (__bf16)f;
    return cv.u;
}
static __device__ __forceinline__ uint32_t pkbf(float a, float b) {
    union { bf16x2 v; uint32_t u; } cv;
    cv.v[0] = (__bf16)a; cv.v[1] = (__bf16)b;
    return cv.u;
}
static __device__ __forceinline__ float exp2_fast(float x) {
#if __has_builtin(__builtin_amdgcn_exp2f)
    return __builtin_amdgcn_exp2f(x);
#else
    float r; asm("v_exp_f32 %0, %1\n\ts_nop 0" : "=v"(r) : "v"(x)); return r;
#endif
}

// ---------------------------------------------------------------------------
// Merged fp32 -> fp16 conversion for x, w_qkv, w_proj (one launch).
// ---------------------------------------------------------------------------
__global__ __launch_bounds__(256)
void conv3(const float* __restrict__ x,  _Float16* __restrict__ Xf,
           const float* __restrict__ wq, _Float16* __restrict__ Wf,
           const float* __restrict__ wp, _Float16* __restrict__ Wpf) {
    const int bid = blockIdx.x;
    const float* src;
    _Float16* dst;
    int base;
    if (bid < 4096)      { src = x;  dst = Xf;  base = bid; }
    else if (bid < 5632) { src = wq; dst = Wf;  base = bid - 4096; }
    else                 { src = wp; dst = Wpf; base = bid - 5632; }
    const int idx = (base * 256 + threadIdx.x) * 8;
    float4 v0 = *(const float4*)(src + idx);
    float4 v1 = *(const float4*)(src + idx + 4);
    half8 h;
    h[0] = (_Float16)v0.x; h[1] = (_Float16)v0.y;
    h[2] = (_Float16)v0.z; h[3] = (_Float16)v0.w;
    h[4] = (_Float16)v1.x; h[5] = (_Float16)v1.y;
    h[6] = (_Float16)v1.z; h[7] = (_Float16)v1.w;
    *(half8*)(dst + idx) = h;
}

// ---------------------------------------------------------------------------
// fp16 MFMA GEMM (r17, unchanged): 128x128 tile, BK=32, 4 waves, 3-buffer
// depth-2 GLL16 pipeline, counted vmcnt(4), XCD grid, compile-time SWP.
// ---------------------------------------------------------------------------
template<int EPI, int SWP>
__global__ __launch_bounds__(256)
void gemm_h(const _Float16* __restrict__ Af, const _Float16* __restrict__ Bf,
            int K, int N, int nbx, int bnoff,
            float* __restrict__ outF, const float* __restrict__ bias,
            unsigned short* __restrict__ Qb, unsigned short* __restrict__ Kb,
            unsigned short* __restrict__ Vt) {
    __shared__ _Float16 lds[3][2][4096];   // [buf][A|B][128*32]

    const int tid = threadIdx.x;
    const int l = tid & 63, wv = tid >> 6;
    const int wr = wv >> 1, wc = wv & 1;
    const int c = l & 15, g = l >> 4;

    const int id = blockIdx.x;
    const int xcd = id & 7, s = id >> 3;
    const int bpx = (gridDim.x >> 3) / nbx;    // by-rows per XCD
    const int by = xcd * bpx + s / nbx, bx = s % nbx;
    const int bm = by * 128, bn = bnoff + bx * 128;

    size_t aoff[2], boff[2];
    int ldsoff[2];
    #pragma unroll
    for (int u = 0; u < 2; ++u) {
        const int i = u * 256 + tid;
        const int row = i >> 2;
        const int gg = (i & 3) ^ ((i >> 3) & 3);    // inverse swizzle on source
        aoff[u] = (size_t)(bm + row) * K + gg * 8;
        boff[u] = (size_t)(bn + row) * K + gg * 8;
        ldsoff[u] = (u * 256 + wv * 64) * 8;
    }

    int offA[4], offB[4];
    #pragma unroll
    for (int m = 0; m < 4; ++m) {
        const int row = wr * 64 + m * 16 + c;
        offA[m] = row * 32 + (g ^ ((row >> 1) & 3)) * 8;
    }
    #pragma unroll
    for (int n = 0; n < 4; ++n) {
        const int row = wc * 64 + n * 16 + c;
        offB[n] = row * 32 + (g ^ ((row >> 1) & 3)) * 8;
    }

    #define GSTAGE(buf, kk) do {                                   \
        _Pragma("unroll")                                          \
        for (int u = 0; u < 2; ++u) {                              \
            GLL16(Af + aoff[u] + (kk), &lds[buf][0][ldsoff[u]]);   \
            GLL16(Bf + boff[u] + (kk), &lds[buf][1][ldsoff[u]]);   \
        }                                                          \
    } while (0)

    f32x4 acc[4][4] = {};
    const int NK = K >> 5;

    GSTAGE(0, 0);
    GSTAGE(1, 32);
    asm volatile("s_waitcnt vmcnt(4)" ::: "memory");
    __builtin_amdgcn_s_barrier();
    __builtin_amdgcn_sched_barrier(0);

    for (int ks = 0; ks < NK; ++ks) {
        const int cur = ks % 3;
        if (ks + 2 < NK) GSTAGE((ks + 2) % 3, (ks + 2) * 32);

        half8 a[4], b[4];
        #pragma unroll
        for (int m = 0; m < 4; ++m) a[m] = *(const half8*)&lds[cur][0][offA[m]];
        #pragma unroll
        for (int n = 0; n < 4; ++n) b[n] = *(const half8*)&lds[cur][1][offB[n]];

        __builtin_amdgcn_s_setprio(1);
        #pragma unroll
        for (int m = 0; m < 4; ++m)
            #pragma unroll
            for (int n = 0; n < 4; ++n) {
                if constexpr (SWP)
                    acc[m][n] = __builtin_amdgcn_mfma_f32_16x16x32_f16(
                        b[n], a[m], acc[m][n], 0, 0, 0);
                else
                    acc[m][n] = __builtin_amdgcn_mfma_f32_16x16x32_f16(
                        a[m], b[n], acc[m][n], 0, 0, 0);
            }
        __builtin_amdgcn_s_setprio(0);

        if (ks + 1 < NK) {
            if (ks + 2 < NK) {
                asm volatile("s_waitcnt vmcnt(4)" ::: "memory");
            } else {
                asm volatile("s_waitcnt vmcnt(0)" ::: "memory");
            }
            __builtin_amdgcn_s_barrier();
            __builtin_amdgcn_sched_barrier(0);
        }
    }
    #undef GSTAGE

    if constexpr (EPI == 0) {
        const int colbase = bn + wc * 64;                   // 64-aligned
        const int which = colbase >> 10;
        const int h = (colbase >> 6) & 15;
        if constexpr (SWP) {
            // Q/K planes: rows = m*16+c, cols = n*16+4g+r -> ushort4 stores
            const float qs = 0.125f * 1.44269504088896340736f;
            unsigned short* plane = (which == 0) ? Qb : Kb;
            const float sc = (which == 0) ? qs : 1.0f;
            #pragma unroll
            for (int m = 0; m < 4; ++m) {
                const int t = bm + wr * 64 + m * 16 + c;
                const int bb = t >> 11, nl = t & 2047;
                unsigned short* rowp = plane +
                    ((size_t)(bb * NHEAD + h) * SEQ + nl) * 64;
                #pragma unroll
                for (int n = 0; n < 4; ++n) {
                    ushort4 o;
                    o.x = f2bfn(acc[m][n][0] * sc);
                    o.y = f2bfn(acc[m][n][1] * sc);
                    o.z = f2bfn(acc[m][n][2] * sc);
                    o.w = f2bfn(acc[m][n][3] * sc);
                    *(ushort4*)(rowp + n * 16 + 4 * g) = o;
                }
            }
        } else {
            // V plane: rows = m*16+4g+r (contiguous nl), cols = n*16+c = d
            #pragma unroll
            for (int m = 0; m < 4; ++m) {
                const int trow0 = bm + wr * 64 + m * 16 + 4 * g;
                const int bb = trow0 >> 11, nl0 = trow0 & 2047;
                #pragma unroll
                for (int n = 0; n < 4; ++n) {
                    const int d = n * 16 + c;
                    ushort4 o;
                    o.x = f2bfn(acc[m][n][0]);
                    o.y = f2bfn(acc[m][n][1]);
                    o.z = f2bfn(acc[m][n][2]);
                    o.w = f2bfn(acc[m][n][3]);
                    *(ushort4*)(Vt + ((size_t)(bb * NHEAD + h) * 64 + d) * SEQ + nl0) = o;
                }
            }
        }
    } else {
        // proj (SWP=1): rows = m*16+c, cols = n*16+4g+r -> float4 + bias
        #pragma unroll
        for (int m = 0; m < 4; ++m) {
            const int t = bm + wr * 64 + m * 16 + c;
            #pragma unroll
            for (int n = 0; n < 4; ++n) {
                const int col0 = bn + wc * 64 + n * 16 + 4 * g;
                float4 bv = *(const float4*)&bias[col0];
                float4 o;
                o.x = acc[m][n][0] + bv.x;
                o.y = acc[m][n][1] + bv.y;
                o.z = acc[m][n][2] + bv.z;
                o.w = acc[m][n][3] + bv.w;
                *(float4*)&outF[(size_t)t * N + col0] = o;
            }
        }
    }
}

// ---------------------------------------------------------------------------
// MFMA flash attention — 64 q-rows PER WAVE this round (m: 2 -> 4).
// The 16 LDS frag reads/tile/wave (8 kf + 8 vb) are independent of the
// wave's q extent, so doubling q-rows/wave halves LDS-pipe cycles per unit
// work (the dominant term: 41us of the 87). Block = 8 waves x 64 = 512
// q-rows; grid 256 = 1 block/CU; K/V staging per CU also halves.
// Per-wave code = r17 pattern (tau' in-register P, swapped PV, half4 out)
// with the m-extent widened; same 2-buffer + __syncthreads structure.
// ---------------------------------------------------------------------------
__global__ __launch_bounds__(512)
void attn_mfma(const unsigned short* __restrict__ Qb, const unsigned short* __restrict__ Kb,
               const unsigned short* __restrict__ Vt, _Float16* __restrict__ Of) {
    __shared__ unsigned short Kl[2][4096];   // [64 row][64 d], rows = tau'-permuted kv
    __shared__ unsigned short Vl[2][4096];   // [64 d][64 kv], natural kv

    const int tid = threadIdx.x;
    const int l = tid & 63, w = tid >> 6;
    const int g = l >> 4, c = l & 15;
    const int sw = (c & 7) << 4;

    // 256 blocks = 8 xcd x 8 bh x 4 q-panels of 512 rows
    const int blk = blockIdx.x;
    const int xcd = blk & 7, s0 = blk >> 3;        // s0 = 0..31
    const int bh = xcd * 8 + (s0 >> 2);
    const int b = bh >> 4, h = bh & 15;
    const int q0 = (s0 & 3) * 512;

    const unsigned short* QbBH = Qb + (size_t)bh * SEQ * 64;
    const unsigned short* KbBH = Kb + (size_t)bh * SEQ * 64;
    const unsigned short* VtBH = Vt + (size_t)bh * 64 * SEQ;

    const int r0 = tid >> 3;
    const int tau0 = (r0 & 32) | ((r0 & 12) << 1) | ((r0 & 16) >> 2) | (r0 & 3);
    const unsigned short* sK0 = KbBH + (size_t)tau0 * 64 + ((tid & 7) ^ (r0 & 7)) * 8;
    const unsigned short* sV0 = VtBH + (size_t)r0 * SEQ + ((tid & 7) ^ (r0 & 7)) * 8;

    #define STAGE(nb, tt) do {                                        \
        GLL16(sK0 + (size_t)(tt) * 4096, (char*)Kl[nb] + tid * 16);   \
        GLL16(sV0 + (tt) * 64,           (char*)Vl[nb] + tid * 16);   \
    } while (0)

    int rdoff[2][4];   // [s][f]: K rows f*16+c / V rows df*16+c
    #pragma unroll
    for (int s = 0; s < 2; ++s)
        #pragma unroll
        for (int f = 0; f < 4; ++f)
            rdoff[s][f] = (f * 16 + c) * 128 + ((g * 16 + s * 64) ^ sw);

    // wave owns q rows q0 + w*64 + m*16 + c, m = 0..3
    short8 qf[4][2];
    #pragma unroll
    for (int m = 0; m < 4; ++m)
        #pragma unroll
        for (int s = 0; s < 2; ++s)
            qf[m][s] = *(const short8*)(QbBH +
                         (size_t)(q0 + w * 64 + m * 16 + c) * 64 + s * 32 + g * 8);

    f32x4 oacc[4][4] = {};
    float l_run[4] = {0.f, 0.f, 0.f, 0.f};

    STAGE(0, 0);
    __syncthreads();

    #define BODY(cur, tt, PF)                                                  \
    {                                                                          \
        if (PF) STAGE(cur ^ 1, (tt) + 1);                                      \
        f32x4 st[4][4] = {};                                                   \
        _Pragma("unroll")                                                      \
        for (int s = 0; s < 2; ++s) {                                          \
            short8 kf[4];                                                      \
            _Pragma("unroll")                                                  \
            for (int f = 0; f < 4; ++f)                                        \
                kf[f] = *(const short8*)((char*)Kl[cur] + rdoff[s][f]);        \
            __builtin_amdgcn_s_setprio(1);                                     \
            _Pragma("unroll")                                                  \
            for (int m = 0; m < 4; ++m)                                        \
                _Pragma("unroll")                                              \
                for (int f = 0; f < 4; ++f)                                    \
                    st[m][f] = __builtin_amdgcn_mfma_f32_16x16x32_bf16(        \
                        kf[f], qf[m][s], st[m][f], 0, 0, 0);                   \
            __builtin_amdgcn_s_setprio(0);                                     \
        }                                                                      \
        short8 pa[4][2];                                                       \
        _Pragma("unroll")                                                      \
        for (int m = 0; m < 4; ++m) {                                          \
            float p[4][4];                                                     \
            _Pragma("unroll")                                                  \
            for (int f = 0; f < 4; ++f)                                        \
                _Pragma("unroll")                                              \
                for (int r = 0; r < 4; ++r)                                    \
                    p[f][r] = exp2_fast(st[m][f][r]);                          \
            float rs = 0.f;                                                    \
            _Pragma("unroll")                                                  \
            for (int f = 0; f < 4; ++f)                                        \
                rs += (p[f][0] + p[f][1]) + (p[f][2] + p[f][3]);               \
            l_run[m] += rs;                                                    \
            uint4 u0, u1;                                                      \
            u0.x = pkbf(p[0][0], p[0][1]); u0.y = pkbf(p[0][2], p[0][3]);      \
            u0.z = pkbf(p[1][0], p[1][1]); u0.w = pkbf(p[1][2], p[1][3]);      \
            u1.x = pkbf(p[2][0], p[2][1]); u1.y = pkbf(p[2][2], p[2][3]);      \
            u1.z = pkbf(p[3][0], p[3][1]); u1.w = pkbf(p[3][2], p[3][3]);      \
            pa[m][0] = *(short8*)&u0;                                          \
            pa[m][1] = *(short8*)&u1;                                          \
        }                                                                      \
        _Pragma("unroll")                                                      \
        for (int s = 0; s < 2; ++s) {                                          \
            short8 vb[4];                                                      \
            _Pragma("unroll")                                                  \
            for (int df = 0; df < 4; ++df)                                     \
                vb[df] = *(const short8*)((char*)Vl[cur] + rdoff[s][df]);      \
            __builtin_amdgcn_s_setprio(1);                                     \
            _Pragma("unroll")                                                  \
            for (int m = 0; m < 4; ++m)                                        \
                _Pragma("unroll")                                              \
                for (int df = 0; df < 4; ++df)                                 \
                    oacc[m][df] = __builtin_amdgcn_mfma_f32_16x16x32_bf16(     \
                        vb[df], pa[m][s], oacc[m][df], 0, 0, 0);               \
            __builtin_amdgcn_s_setprio(0);                                     \
        }                                                                      \
        __syncthreads();                                                       \
    }

    for (int t = 0; t < NT; t += 2) {
        BODY(0, t, true);
        BODY(1, t + 1, (t + 2 < NT));
    }
    #undef BODY
    #undef STAGE

    // ---- epilogue: lane's own l (q = c); half4 stores over consecutive d ----
    #pragma unroll
    for (int m = 0; m < 4; ++m) {
        l_run[m] += __shfl_xor(l_run[m], 16);
        l_run[m] += __shfl_xor(l_run[m], 32);
        const float iv = __builtin_amdgcn_rcpf(l_run[m]);
        const size_t t = (size_t)(b * SEQ + q0 + w * 64 + m * 16 + c);
        _Float16* orow = Of + t * 1024 + h * 64;
        #pragma unroll
        for (int df = 0; df < 4; ++df) {
            half4 o;
            o[0] = (_Float16)(oacc[m][df][0] * iv);
            o[1] = (_Float16)(oacc[m][df][1] * iv);
            o[2] = (_Float16)(oacc[m][df][2] * iv);
            o[3] = (_Float16)(oacc[m][df][3] * iv);
            *(half4*)(orow + df * 16 + 4 * g) = o;
        }
    }
}

// ---------------------------------------------------------------------------
extern "C" void kernel_launch(void* const* d_in, const int* in_sizes, int n_in,
                              void* d_out, int out_size, void* d_ws, size_t ws_size,
                              hipStream_t stream) {
    const float* x      = (const float*)d_in[0];
    const float* w_qkv  = (const float*)d_in[1];
    const float* w_proj = (const float*)d_in[2];
    const float* b_proj = (const float*)d_in[3];
    float* out = (float*)d_out;

    char* ws = (char*)d_ws;
    const size_t MB = 1024 * 1024;
    _Float16* Xf  = (_Float16*)(ws);             // 16 MB
    _Float16* Of  = Xf;                          // alias: X dead after qkv GEMM
    _Float16* Wf  = (_Float16*)(ws + 16 * MB);   // 6 MB
    _Float16* Wpf = (_Float16*)(ws + 22 * MB);   // 2 MB
    unsigned short* Qb = (unsigned short*)(ws + 24 * MB);  // 16 MB
    unsigned short* Kb = (unsigned short*)(ws + 40 * MB);  // 16 MB
    unsigned short* Vt = (unsigned short*)(ws + 56 * MB);  // 16 MB -> 72 MB total

    // 1) fp16 conversions (single launch)
    conv3<<<6144, 256, 0, stream>>>(x, Xf, w_qkv, Wf, w_proj, Wpf);

    // 2a) qkv GEMM, Q/K columns (swapped, ushort4 epilogue)
    gemm_h<0, 1><<<1024, 256, 0, stream>>>(
        Xf, Wf, 1024, 3072, 16, 0, nullptr, nullptr, Qb, Kb, Vt);
    // 2b) qkv GEMM, V columns (unswapped, ushort4-over-nl epilogue)
    gemm_h<0, 0><<<512, 256, 0, stream>>>(
        Xf, Wf, 1024, 3072, 8, 2048, nullptr, nullptr, Qb, Kb, Vt);

    // 3) flash attention (64 q-rows/wave, 1 blk/CU, in-register P) -> Of
    attn_mfma<<<256, 512, 0, stream>>>(Qb, Kb, Vt, Of);

    // 4) proj GEMM (float4 epilogue) + bias -> out
    gemm_h<1, 1><<<512, 256, 0, stream>>>(
        Of, Wpf, 1024, 1024, 8, 0, out, b_proj, nullptr, nullptr, nullptr);
}

// Round 22
// 177.225 us; speedup vs baseline: 1.1155x; 1.0196x over previous
//
#include <hip/hip_runtime.h>
#include <stdint.h>

#define NHEAD 16
#define SEQ 2048
#define BATCH 4
#define NT (SEQ / 64)   // 32 kv tiles of 64

typedef short short8 __attribute__((ext_vector_type(8)));     // 8 bf16 (4 VGPRs)
typedef _Float16 half8 __attribute__((ext_vector_type(8)));   // 8 fp16 (4 VGPRs)
typedef _Float16 half4 __attribute__((ext_vector_type(4)));   // 4 fp16 (8B)
typedef float f32x4  __attribute__((ext_vector_type(4)));     // MFMA accumulator
typedef __bf16 bf16x2 __attribute__((ext_vector_type(2)));

typedef const __attribute__((address_space(1))) void* gas_t;
typedef __attribute__((address_space(3))) void* las_t;
#define GLL16(g, s) __builtin_amdgcn_global_load_lds((gas_t)(g), (las_t)(s), 16, 0, 0)

static __device__ __forceinline__ unsigned short f2bfn(float f) {
    union { __bf16 b; unsigned short u; } cv;
    cv.b = (__bf16)f;
    return cv.u;
}
static __device__ __forceinline__ uint32_t pkbf(float a, float b) {
    union { bf16x2 v; uint32_t u; } cv;
    cv.v[0] = (__bf16)a; cv.v[1] = (__bf16)b;
    return cv.u;
}
static __device__ __forceinline__ float exp2_fast(float x) {
#if __has_builtin(__builtin_amdgcn_exp2f)
    return __builtin_amdgcn_exp2f(x);
#else
    float r; asm("v_exp_f32 %0, %1\n\ts_nop 0" : "=v"(r) : "v"(x)); return r;
#endif
}

// ---------------------------------------------------------------------------
// Merged fp32 -> fp16 conversion for x, w_qkv, w_proj (one launch).
// ---------------------------------------------------------------------------
__global__ __launch_bounds__(256)
void conv3(const float* __restrict__ x,  _Float16* __restrict__ Xf,
           const float* __restrict__ wq, _Float16* __restrict__ Wf,
           const float* __restrict__ wp, _Float16* __restrict__ Wpf) {
    const int bid = blockIdx.x;
    const float* src;
    _Float16* dst;
    int base;
    if (bid < 4096)      { src = x;  dst = Xf;  base = bid; }
    else if (bid < 5632) { src = wq; dst = Wf;  base = bid - 4096; }
    else                 { src = wp; dst = Wpf; base = bid - 5632; }
    const int idx = (base * 256 + threadIdx.x) * 8;
    float4 v0 = *(const float4*)(src + idx);
    float4 v1 = *(const float4*)(src + idx + 4);
    half8 h;
    h[0] = (_Float16)v0.x; h[1] = (_Float16)v0.y;
    h[2] = (_Float16)v0.z; h[3] = (_Float16)v0.w;
    h[4] = (_Float16)v1.x; h[5] = (_Float16)v1.y;
    h[6] = (_Float16)v1.z; h[7] = (_Float16)v1.w;
    *(half8*)(dst + idx) = h;
}

// ---------------------------------------------------------------------------
// fp16 MFMA GEMM — WIDE WAVES this round: 256x128 macro-tile, 256 thr =
// 4 waves (2M x 2N), each wave owns 128x64 (8x4 frags): 12 ds_read_b128 per
// K-step for 32 MFMA (was 8 for 16) -> LDS cycles per unit work x0.75, and
// half the blocks -> A staged once per 256 rows. Same 3-buffer depth-2
// GLL16 pipeline with counted vmcnt(6) (6 loads/step). LDS 3x24KB = 72KB
// -> 2 blocks/CU. Compile-time SWP operand order + vectorized epilogues.
// ---------------------------------------------------------------------------
template<int EPI, int SWP>
__global__ __launch_bounds__(256, 2)
void gemm_h(const _Float16* __restrict__ Af, const _Float16* __restrict__ Bf,
            int K, int N, int nbx, int bnoff,
            float* __restrict__ outF, const float* __restrict__ bias,
            unsigned short* __restrict__ Qb, unsigned short* __restrict__ Kb,
            unsigned short* __restrict__ Vt) {
    __shared__ _Float16 lds[3][12288];   // [buf][ A 256x32 | B 128x32 ]

    const int tid = threadIdx.x;
    const int l = tid & 63, wv = tid >> 6;
    const int wm = wv >> 1, wn = wv & 1;       // 2 M-waves x 2 N-waves
    const int c = l & 15, g = l >> 4;

    const int id = blockIdx.x;
    const int xcd = id & 7, s = id >> 3;
    const int bpx = (gridDim.x >> 3) / nbx;    // by-rows per XCD
    const int by = xcd * bpx + s / nbx, bx = s % nbx;
    const int bm = by * 256, bn = bnoff + bx * 128;

    // staging: A = 1024 16B-chunks (4/thread), B = 512 (2/thread);
    // source column pre-swizzled gg = (i&3) ^ ((row>>1)&3); dest linear.
    size_t aoff[4], boff[2];
    int ldsA[4], ldsB[2];
    #pragma unroll
    for (int u = 0; u < 4; ++u) {
        const int i = u * 256 + tid;
        const int row = i >> 2;
        const int gg = (i & 3) ^ ((row >> 1) & 3);
        aoff[u] = (size_t)(bm + row) * K + gg * 8;
        ldsA[u] = (u * 256 + wv * 64) * 8;
    }
    #pragma unroll
    for (int u = 0; u < 2; ++u) {
        const int i = u * 256 + tid;
        const int row = i >> 2;
        const int gg = (i & 3) ^ ((row >> 1) & 3);
        boff[u] = (size_t)(bn + row) * K + gg * 8;
        ldsB[u] = 8192 + (u * 256 + wv * 64) * 8;
    }

    // frag read offsets (elements), constant across K
    int offA[8], offB[4];
    #pragma unroll
    for (int m = 0; m < 8; ++m) {
        const int row = wm * 128 + m * 16 + c;
        offA[m] = row * 32 + (g ^ ((row >> 1) & 3)) * 8;
    }
    #pragma unroll
    for (int n = 0; n < 4; ++n) {
        const int row = wn * 64 + n * 16 + c;
        offB[n] = 8192 + row * 32 + (g ^ ((row >> 1) & 3)) * 8;
    }

    #define GSTAGE(buf, kk) do {                              \
        _Pragma("unroll")                                     \
        for (int u = 0; u < 4; ++u)                           \
            GLL16(Af + aoff[u] + (kk), &lds[buf][ldsA[u]]);   \
        _Pragma("unroll")                                     \
        for (int u = 0; u < 2; ++u)                           \
            GLL16(Bf + boff[u] + (kk), &lds[buf][ldsB[u]]);   \
    } while (0)

    f32x4 acc[8][4] = {};
    const int NK = K >> 5;

    GSTAGE(0, 0);
    GSTAGE(1, 32);
    asm volatile("s_waitcnt vmcnt(6)" ::: "memory");   // buf0 ready, buf1 in flight
    __builtin_amdgcn_s_barrier();
    __builtin_amdgcn_sched_barrier(0);

    for (int ks = 0; ks < NK; ++ks) {
        const int cur = ks % 3;
        if (ks + 2 < NK) GSTAGE((ks + 2) % 3, (ks + 2) * 32);   // depth-2 prefetch

        half8 a[8], b[4];
        #pragma unroll
        for (int m = 0; m < 8; ++m) a[m] = *(const half8*)&lds[cur][offA[m]];
        #pragma unroll
        for (int n = 0; n < 4; ++n) b[n] = *(const half8*)&lds[cur][offB[n]];

        __builtin_amdgcn_s_setprio(1);
        #pragma unroll
        for (int m = 0; m < 8; ++m)
            #pragma unroll
            for (int n = 0; n < 4; ++n) {
                if constexpr (SWP)
                    acc[m][n] = __builtin_amdgcn_mfma_f32_16x16x32_f16(
                        b[n], a[m], acc[m][n], 0, 0, 0);
                else
                    acc[m][n] = __builtin_amdgcn_mfma_f32_16x16x32_f16(
                        a[m], b[n], acc[m][n], 0, 0, 0);
            }
        __builtin_amdgcn_s_setprio(0);

        if (ks + 1 < NK) {
            if (ks + 2 < NK) {
                asm volatile("s_waitcnt vmcnt(6)" ::: "memory");  // next buf ready
            } else {
                asm volatile("s_waitcnt vmcnt(0)" ::: "memory");  // tail drain
            }
            __builtin_amdgcn_s_barrier();
            __builtin_amdgcn_sched_barrier(0);
        }
    }
    #undef GSTAGE

    if constexpr (EPI == 0) {
        const int colbase = bn + wn * 64;                   // 64-aligned
        const int which = colbase >> 10;
        const int h = (colbase >> 6) & 15;
        if constexpr (SWP) {
            // Q/K planes: rows = m*16+c, cols = n*16+4g+r -> ushort4 stores
            const float qs = 0.125f * 1.44269504088896340736f;
            unsigned short* plane = (which == 0) ? Qb : Kb;
            const float sc = (which == 0) ? qs : 1.0f;
            #pragma unroll
            for (int m = 0; m < 8; ++m) {
                const int t = bm + wm * 128 + m * 16 + c;
                const int bb = t >> 11, nl = t & 2047;
                unsigned short* rowp = plane +
                    ((size_t)(bb * NHEAD + h) * SEQ + nl) * 64;
                #pragma unroll
                for (int n = 0; n < 4; ++n) {
                    ushort4 o;
                    o.x = f2bfn(acc[m][n][0] * sc);
                    o.y = f2bfn(acc[m][n][1] * sc);
                    o.z = f2bfn(acc[m][n][2] * sc);
                    o.w = f2bfn(acc[m][n][3] * sc);
                    *(ushort4*)(rowp + n * 16 + 4 * g) = o;
                }
            }
        } else {
            // V plane: rows = m*16+4g+r (contiguous nl), cols = n*16+c = d
            #pragma unroll
            for (int m = 0; m < 8; ++m) {
                const int trow0 = bm + wm * 128 + m * 16 + 4 * g;
                const int bb = trow0 >> 11, nl0 = trow0 & 2047;
                #pragma unroll
                for (int n = 0; n < 4; ++n) {
                    const int d = n * 16 + c;
                    ushort4 o;
                    o.x = f2bfn(acc[m][n][0]);
                    o.y = f2bfn(acc[m][n][1]);
                    o.z = f2bfn(acc[m][n][2]);
                    o.w = f2bfn(acc[m][n][3]);
                    *(ushort4*)(Vt + ((size_t)(bb * NHEAD + h) * 64 + d) * SEQ + nl0) = o;
                }
            }
        }
    } else {
        // proj (SWP=1): rows = m*16+c, cols = n*16+4g+r -> float4 + bias
        #pragma unroll
        for (int m = 0; m < 8; ++m) {
            const int t = bm + wm * 128 + m * 16 + c;
            #pragma unroll
            for (int n = 0; n < 4; ++n) {
                const int col0 = bn + wn * 64 + n * 16 + 4 * g;
                float4 bv = *(const float4*)&bias[col0];
                float4 o;
                o.x = acc[m][n][0] + bv.x;
                o.y = acc[m][n][1] + bv.y;
                o.z = acc[m][n][2] + bv.z;
                o.w = acc[m][n][3] + bv.w;
                *(float4*)&outF[(size_t)t * N + col0] = o;
            }
        }
    }
}

// ---------------------------------------------------------------------------
// MFMA flash attention (r21, unchanged): 64 q-rows/wave, 8 waves x 512 rows,
// 1 blk/CU grid, tau' in-register P, swapped PV, half4 stores.
// ---------------------------------------------------------------------------
__global__ __launch_bounds__(512)
void attn_mfma(const unsigned short* __restrict__ Qb, const unsigned short* __restrict__ Kb,
               const unsigned short* __restrict__ Vt, _Float16* __restrict__ Of) {
    __shared__ unsigned short Kl[2][4096];   // [64 row][64 d], rows = tau'-permuted kv
    __shared__ unsigned short Vl[2][4096];   // [64 d][64 kv], natural kv

    const int tid = threadIdx.x;
    const int l = tid & 63, w = tid >> 6;
    const int g = l >> 4, c = l & 15;
    const int sw = (c & 7) << 4;

    const int blk = blockIdx.x;
    const int xcd = blk & 7, s0 = blk >> 3;        // s0 = 0..31
    const int bh = xcd * 8 + (s0 >> 2);
    const int b = bh >> 4, h = bh & 15;
    const int q0 = (s0 & 3) * 512;

    const unsigned short* QbBH = Qb + (size_t)bh * SEQ * 64;
    const unsigned short* KbBH = Kb + (size_t)bh * SEQ * 64;
    const unsigned short* VtBH = Vt + (size_t)bh * 64 * SEQ;

    const int r0 = tid >> 3;
    const int tau0 = (r0 & 32) | ((r0 & 12) << 1) | ((r0 & 16) >> 2) | (r0 & 3);
    const unsigned short* sK0 = KbBH + (size_t)tau0 * 64 + ((tid & 7) ^ (r0 & 7)) * 8;
    const unsigned short* sV0 = VtBH + (size_t)r0 * SEQ + ((tid & 7) ^ (r0 & 7)) * 8;

    #define STAGE(nb, tt) do {                                        \
        GLL16(sK0 + (size_t)(tt) * 4096, (char*)Kl[nb] + tid * 16);   \
        GLL16(sV0 + (tt) * 64,           (char*)Vl[nb] + tid * 16);   \
    } while (0)

    int rdoff[2][4];
    #pragma unroll
    for (int s = 0; s < 2; ++s)
        #pragma unroll
        for (int f = 0; f < 4; ++f)
            rdoff[s][f] = (f * 16 + c) * 128 + ((g * 16 + s * 64) ^ sw);

    short8 qf[4][2];
    #pragma unroll
    for (int m = 0; m < 4; ++m)
        #pragma unroll
        for (int s = 0; s < 2; ++s)
            qf[m][s] = *(const short8*)(QbBH +
                         (size_t)(q0 + w * 64 + m * 16 + c) * 64 + s * 32 + g * 8);

    f32x4 oacc[4][4] = {};
    float l_run[4] = {0.f, 0.f, 0.f, 0.f};

    STAGE(0, 0);
    __syncthreads();

    #define BODY(cur, tt, PF)                                                  \
    {                                                                          \
        if (PF) STAGE(cur ^ 1, (tt) + 1);                                      \
        f32x4 st[4][4] = {};                                                   \
        _Pragma("unroll")                                                      \
        for (int s = 0; s < 2; ++s) {                                          \
            short8 kf[4];                                                      \
            _Pragma("unroll")                                                  \
            for (int f = 0; f < 4; ++f)                                        \
                kf[f] = *(const short8*)((char*)Kl[cur] + rdoff[s][f]);        \
            __builtin_amdgcn_s_setprio(1);                                     \
            _Pragma("unroll")                                                  \
            for (int m = 0; m < 4; ++m)                                        \
                _Pragma("unroll")                                              \
                for (int f = 0; f < 4; ++f)                                    \
                    st[m][f] = __builtin_amdgcn_mfma_f32_16x16x32_bf16(        \
                        kf[f], qf[m][s], st[m][f], 0, 0, 0);                   \
            __builtin_amdgcn_s_setprio(0);                                     \
        }                                                                      \
        short8 pa[4][2];                                                       \
        _Pragma("unroll")                                                      \
        for (int m = 0; m < 4; ++m) {                                          \
            float p[4][4];                                                     \
            _Pragma("unroll")                                                  \
            for (int f = 0; f < 4; ++f)                                        \
                _Pragma("unroll")                                              \
                for (int r = 0; r < 4; ++r)                                    \
                    p[f][r] = exp2_fast(st[m][f][r]);                          \
            float rs = 0.f;                                                    \
            _Pragma("unroll")                                                  \
            for (int f = 0; f < 4; ++f)                                        \
                rs += (p[f][0] + p[f][1]) + (p[f][2] + p[f][3]);               \
            l_run[m] += rs;                                                    \
            uint4 u0, u1;                                                      \
            u0.x = pkbf(p[0][0], p[0][1]); u0.y = pkbf(p[0][2], p[0][3]);      \
            u0.z = pkbf(p[1][0], p[1][1]); u0.w = pkbf(p[1][2], p[1][3]);      \
            u1.x = pkbf(p[2][0], p[2][1]); u1.y = pkbf(p[2][2], p[2][3]);      \
            u1.z = pkbf(p[3][0], p[3][1]); u1.w = pkbf(p[3][2], p[3][3]);      \
            pa[m][0] = *(short8*)&u0;                                          \
            pa[m][1] = *(short8*)&u1;                                          \
        }                                                                      \
        _Pragma("unroll")                                                      \
        for (int s = 0; s < 2; ++s) {                                          \
            short8 vb[4];                                                      \
            _Pragma("unroll")                                                  \
            for (int df = 0; df < 4; ++df)                                     \
                vb[df] = *(const short8*)((char*)Vl[cur] + rdoff[s][df]);      \
            __builtin_amdgcn_s_setprio(1);                                     \
            _Pragma("unroll")                                                  \
            for (int m = 0; m < 4; ++m)                                        \
                _Pragma("unroll")                                              \
                for (int df = 0; df < 4; ++df)                                 \
                    oacc[m][df] = __builtin_amdgcn_mfma_f32_16x16x32_bf16(     \
                        vb[df], pa[m][s], oacc[m][df], 0, 0, 0);               \
            __builtin_amdgcn_s_setprio(0);                                     \
        }                                                                      \
        __syncthreads();                                                       \
    }

    for (int t = 0; t < NT; t += 2) {
        BODY(0, t, true);
        BODY(1, t + 1, (t + 2 < NT));
    }
    #undef BODY
    #undef STAGE

    #pragma unroll
    for (int m = 0; m < 4; ++m) {
        l_run[m] += __shfl_xor(l_run[m], 16);
        l_run[m] += __shfl_xor(l_run[m], 32);
        const float iv = __builtin_amdgcn_rcpf(l_run[m]);
        const size_t t = (size_t)(b * SEQ + q0 + w * 64 + m * 16 + c);
        _Float16* orow = Of + t * 1024 + h * 64;
        #pragma unroll
        for (int df = 0; df < 4; ++df) {
            half4 o;
            o[0] = (_Float16)(oacc[m][df][0] * iv);
            o[1] = (_Float16)(oacc[m][df][1] * iv);
            o[2] = (_Float16)(oacc[m][df][2] * iv);
            o[3] = (_Float16)(oacc[m][df][3] * iv);
            *(half4*)(orow + df * 16 + 4 * g) = o;
        }
    }
}

// ---------------------------------------------------------------------------
extern "C" void kernel_launch(void* const* d_in, const int* in_sizes, int n_in,
                              void* d_out, int out_size, void* d_ws, size_t ws_size,
                              hipStream_t stream) {
    const float* x      = (const float*)d_in[0];
    const float* w_qkv  = (const float*)d_in[1];
    const float* w_proj = (const float*)d_in[2];
    const float* b_proj = (const float*)d_in[3];
    float* out = (float*)d_out;

    char* ws = (char*)d_ws;
    const size_t MB = 1024 * 1024;
    _Float16* Xf  = (_Float16*)(ws);             // 16 MB
    _Float16* Of  = Xf;                          // alias: X dead after qkv GEMM
    _Float16* Wf  = (_Float16*)(ws + 16 * MB);   // 6 MB
    _Float16* Wpf = (_Float16*)(ws + 22 * MB);   // 2 MB
    unsigned short* Qb = (unsigned short*)(ws + 24 * MB);  // 16 MB
    unsigned short* Kb = (unsigned short*)(ws + 40 * MB);  // 16 MB
    unsigned short* Vt = (unsigned short*)(ws + 56 * MB);  // 16 MB -> 72 MB total

    // 1) fp16 conversions (single launch)
    conv3<<<6144, 256, 0, stream>>>(x, Xf, w_qkv, Wf, w_proj, Wpf);

    // 2a) qkv GEMM, Q/K columns (256x128 wide-wave, swapped epilogue)
    gemm_h<0, 1><<<512, 256, 0, stream>>>(
        Xf, Wf, 1024, 3072, 16, 0, nullptr, nullptr, Qb, Kb, Vt);
    // 2b) qkv GEMM, V columns (256x128 wide-wave, unswapped epilogue)
    gemm_h<0, 0><<<256, 256, 0, stream>>>(
        Xf, Wf, 1024, 3072, 8, 2048, nullptr, nullptr, Qb, Kb, Vt);

    // 3) flash attention (64 q-rows/wave, in-register P) -> Of
    attn_mfma<<<256, 512, 0, stream>>>(Qb, Kb, Vt, Of);

    // 4) proj GEMM (256x128 wide-wave, float4 epilogue) + bias -> out
    gemm_h<1, 1><<<256, 256, 0, stream>>>(
        Of, Wpf, 1024, 1024, 8, 0, out, b_proj, nullptr, nullptr, nullptr);
}

// Round 23
// 175.768 us; speedup vs baseline: 1.1247x; 1.0083x over previous
//
#include <hip/hip_runtime.h>
#include <stdint.h>

#define NHEAD 16
#define SEQ 2048
#define BATCH 4
#define NT (SEQ / 64)   // 32 kv tiles of 64

typedef short short8 __attribute__((ext_vector_type(8)));     // 8 bf16 (4 VGPRs)
typedef _Float16 half8 __attribute__((ext_vector_type(8)));   // 8 fp16 (4 VGPRs)
typedef _Float16 half4 __attribute__((ext_vector_type(4)));   // 4 fp16 (8B)
typedef float f32x4  __attribute__((ext_vector_type(4)));     // MFMA accumulator
typedef __bf16 bf16x2 __attribute__((ext_vector_type(2)));

typedef const __attribute__((address_space(1))) void* gas_t;
typedef __attribute__((address_space(3))) void* las_t;
#define GLL16(g, s) __builtin_amdgcn_global_load_lds((gas_t)(g), (las_t)(s), 16, 0, 0)

static __device__ __forceinline__ unsigned short f2bfn(float f) {
    union { __bf16 b; unsigned short u; } cv;
    cv.b = (__bf16)f;
    return cv.u;
}
static __device__ __forceinline__ uint32_t pkbf(float a, float b) {
    union { bf16x2 v; uint32_t u; } cv;
    cv.v[0] = (__bf16)a; cv.v[1] = (__bf16)b;
    return cv.u;
}
static __device__ __forceinline__ float exp2_fast(float x) {
#if __has_builtin(__builtin_amdgcn_exp2f)
    return __builtin_amdgcn_exp2f(x);
#else
    float r; asm("v_exp_f32 %0, %1\n\ts_nop 0" : "=v"(r) : "v"(x)); return r;
#endif
}

// ---------------------------------------------------------------------------
// Merged fp32 -> fp16 conversion for x, w_qkv, w_proj (one launch).
// ---------------------------------------------------------------------------
__global__ __launch_bounds__(256)
void conv3(const float* __restrict__ x,  _Float16* __restrict__ Xf,
           const float* __restrict__ wq, _Float16* __restrict__ Wf,
           const float* __restrict__ wp, _Float16* __restrict__ Wpf) {
    const int bid = blockIdx.x;
    const float* src;
    _Float16* dst;
    int base;
    if (bid < 4096)      { src = x;  dst = Xf;  base = bid; }
    else if (bid < 5632) { src = wq; dst = Wf;  base = bid - 4096; }
    else                 { src = wp; dst = Wpf; base = bid - 5632; }
    const int idx = (base * 256 + threadIdx.x) * 8;
    float4 v0 = *(const float4*)(src + idx);
    float4 v1 = *(const float4*)(src + idx + 4);
    half8 h;
    h[0] = (_Float16)v0.x; h[1] = (_Float16)v0.y;
    h[2] = (_Float16)v0.z; h[3] = (_Float16)v0.w;
    h[4] = (_Float16)v1.x; h[5] = (_Float16)v1.y;
    h[6] = (_Float16)v1.z; h[7] = (_Float16)v1.w;
    *(half8*)(dst + idx) = h;
}

// ---------------------------------------------------------------------------
// fp16 MFMA GEMM (r22, unchanged): 256x128 macro-tile, 4 waves (2Mx2N),
// wave owns 128x64 (8x4 frags), 3-buffer depth-2 GLL16, vmcnt(6), XCD grid,
// compile-time SWP operand order + vectorized epilogues.
// ---------------------------------------------------------------------------
template<int EPI, int SWP>
__global__ __launch_bounds__(256, 2)
void gemm_h(const _Float16* __restrict__ Af, const _Float16* __restrict__ Bf,
            int K, int N, int nbx, int bnoff,
            float* __restrict__ outF, const float* __restrict__ bias,
            unsigned short* __restrict__ Qb, unsigned short* __restrict__ Kb,
            unsigned short* __restrict__ Vt) {
    __shared__ _Float16 lds[3][12288];   // [buf][ A 256x32 | B 128x32 ]

    const int tid = threadIdx.x;
    const int l = tid & 63, wv = tid >> 6;
    const int wm = wv >> 1, wn = wv & 1;       // 2 M-waves x 2 N-waves
    const int c = l & 15, g = l >> 4;

    const int id = blockIdx.x;
    const int xcd = id & 7, s = id >> 3;
    const int bpx = (gridDim.x >> 3) / nbx;    // by-rows per XCD
    const int by = xcd * bpx + s / nbx, bx = s % nbx;
    const int bm = by * 256, bn = bnoff + bx * 128;

    size_t aoff[4], boff[2];
    int ldsA[4], ldsB[2];
    #pragma unroll
    for (int u = 0; u < 4; ++u) {
        const int i = u * 256 + tid;
        const int row = i >> 2;
        const int gg = (i & 3) ^ ((row >> 1) & 3);
        aoff[u] = (size_t)(bm + row) * K + gg * 8;
        ldsA[u] = (u * 256 + wv * 64) * 8;
    }
    #pragma unroll
    for (int u = 0; u < 2; ++u) {
        const int i = u * 256 + tid;
        const int row = i >> 2;
        const int gg = (i & 3) ^ ((row >> 1) & 3);
        boff[u] = (size_t)(bn + row) * K + gg * 8;
        ldsB[u] = 8192 + (u * 256 + wv * 64) * 8;
    }

    int offA[8], offB[4];
    #pragma unroll
    for (int m = 0; m < 8; ++m) {
        const int row = wm * 128 + m * 16 + c;
        offA[m] = row * 32 + (g ^ ((row >> 1) & 3)) * 8;
    }
    #pragma unroll
    for (int n = 0; n < 4; ++n) {
        const int row = wn * 64 + n * 16 + c;
        offB[n] = 8192 + row * 32 + (g ^ ((row >> 1) & 3)) * 8;
    }

    #define GSTAGE(buf, kk) do {                              \
        _Pragma("unroll")                                     \
        for (int u = 0; u < 4; ++u)                           \
            GLL16(Af + aoff[u] + (kk), &lds[buf][ldsA[u]]);   \
        _Pragma("unroll")                                     \
        for (int u = 0; u < 2; ++u)                           \
            GLL16(Bf + boff[u] + (kk), &lds[buf][ldsB[u]]);   \
    } while (0)

    f32x4 acc[8][4] = {};
    const int NK = K >> 5;

    GSTAGE(0, 0);
    GSTAGE(1, 32);
    asm volatile("s_waitcnt vmcnt(6)" ::: "memory");
    __builtin_amdgcn_s_barrier();
    __builtin_amdgcn_sched_barrier(0);

    for (int ks = 0; ks < NK; ++ks) {
        const int cur = ks % 3;
        if (ks + 2 < NK) GSTAGE((ks + 2) % 3, (ks + 2) * 32);

        half8 a[8], b[4];
        #pragma unroll
        for (int m = 0; m < 8; ++m) a[m] = *(const half8*)&lds[cur][offA[m]];
        #pragma unroll
        for (int n = 0; n < 4; ++n) b[n] = *(const half8*)&lds[cur][offB[n]];

        __builtin_amdgcn_s_setprio(1);
        #pragma unroll
        for (int m = 0; m < 8; ++m)
            #pragma unroll
            for (int n = 0; n < 4; ++n) {
                if constexpr (SWP)
                    acc[m][n] = __builtin_amdgcn_mfma_f32_16x16x32_f16(
                        b[n], a[m], acc[m][n], 0, 0, 0);
                else
                    acc[m][n] = __builtin_amdgcn_mfma_f32_16x16x32_f16(
                        a[m], b[n], acc[m][n], 0, 0, 0);
            }
        __builtin_amdgcn_s_setprio(0);

        if (ks + 1 < NK) {
            if (ks + 2 < NK) {
                asm volatile("s_waitcnt vmcnt(6)" ::: "memory");
            } else {
                asm volatile("s_waitcnt vmcnt(0)" ::: "memory");
            }
            __builtin_amdgcn_s_barrier();
            __builtin_amdgcn_sched_barrier(0);
        }
    }
    #undef GSTAGE

    if constexpr (EPI == 0) {
        const int colbase = bn + wn * 64;                   // 64-aligned
        const int which = colbase >> 10;
        const int h = (colbase >> 6) & 15;
        if constexpr (SWP) {
            const float qs = 0.125f * 1.44269504088896340736f;
            unsigned short* plane = (which == 0) ? Qb : Kb;
            const float sc = (which == 0) ? qs : 1.0f;
            #pragma unroll
            for (int m = 0; m < 8; ++m) {
                const int t = bm + wm * 128 + m * 16 + c;
                const int bb = t >> 11, nl = t & 2047;
                unsigned short* rowp = plane +
                    ((size_t)(bb * NHEAD + h) * SEQ + nl) * 64;
                #pragma unroll
                for (int n = 0; n < 4; ++n) {
                    ushort4 o;
                    o.x = f2bfn(acc[m][n][0] * sc);
                    o.y = f2bfn(acc[m][n][1] * sc);
                    o.z = f2bfn(acc[m][n][2] * sc);
                    o.w = f2bfn(acc[m][n][3] * sc);
                    *(ushort4*)(rowp + n * 16 + 4 * g) = o;
                }
            }
        } else {
            #pragma unroll
            for (int m = 0; m < 8; ++m) {
                const int trow0 = bm + wm * 128 + m * 16 + 4 * g;
                const int bb = trow0 >> 11, nl0 = trow0 & 2047;
                #pragma unroll
                for (int n = 0; n < 4; ++n) {
                    const int d = n * 16 + c;
                    ushort4 o;
                    o.x = f2bfn(acc[m][n][0]);
                    o.y = f2bfn(acc[m][n][1]);
                    o.z = f2bfn(acc[m][n][2]);
                    o.w = f2bfn(acc[m][n][3]);
                    *(ushort4*)(Vt + ((size_t)(bb * NHEAD + h) * 64 + d) * SEQ + nl0) = o;
                }
            }
        }
    } else {
        #pragma unroll
        for (int m = 0; m < 8; ++m) {
            const int t = bm + wm * 128 + m * 16 + c;
            #pragma unroll
            for (int n = 0; n < 4; ++n) {
                const int col0 = bn + wn * 64 + n * 16 + 4 * g;
                float4 bv = *(const float4*)&bias[col0];
                float4 o;
                o.x = acc[m][n][0] + bv.x;
                o.y = acc[m][n][1] + bv.y;
                o.z = acc[m][n][2] + bv.z;
                o.w = acc[m][n][3] + bv.w;
                *(float4*)&outF[(size_t)t * N + col0] = o;
            }
        }
    }
}

// ---------------------------------------------------------------------------
// MFMA flash attention — VALU diet this round (structure = r21/r22):
//  * shared-zero C operand: s=0 QK MFMAs take one z4 register quad as C-in,
//    removing ~60 v_movs/tile of st zero-init.
//  * l on the matrix pipe, swapped orientation: lacc[m] += mfma(ones, pa)
//    -> out[*][col=c] = full-kv sum of P column q=c. Removes 48 rowsum
//    adds/tile AND the epilogue cross-lane shuffles; +8 MFMA/tile (pipe
//    at 38%). l = sum of bf16-rounded p (rel shift ~4e-5, negligible).
// ---------------------------------------------------------------------------
__global__ __launch_bounds__(512)
void attn_mfma(const unsigned short* __restrict__ Qb, const unsigned short* __restrict__ Kb,
               const unsigned short* __restrict__ Vt, _Float16* __restrict__ Of) {
    __shared__ unsigned short Kl[2][4096];   // [64 row][64 d], rows = tau'-permuted kv
    __shared__ unsigned short Vl[2][4096];   // [64 d][64 kv], natural kv

    const int tid = threadIdx.x;
    const int l = tid & 63, w = tid >> 6;
    const int g = l >> 4, c = l & 15;
    const int sw = (c & 7) << 4;

    const int blk = blockIdx.x;
    const int xcd = blk & 7, s0 = blk >> 3;        // s0 = 0..31
    const int bh = xcd * 8 + (s0 >> 2);
    const int b = bh >> 4, h = bh & 15;
    const int q0 = (s0 & 3) * 512;

    const unsigned short* QbBH = Qb + (size_t)bh * SEQ * 64;
    const unsigned short* KbBH = Kb + (size_t)bh * SEQ * 64;
    const unsigned short* VtBH = Vt + (size_t)bh * 64 * SEQ;

    const int r0 = tid >> 3;
    const int tau0 = (r0 & 32) | ((r0 & 12) << 1) | ((r0 & 16) >> 2) | (r0 & 3);
    const unsigned short* sK0 = KbBH + (size_t)tau0 * 64 + ((tid & 7) ^ (r0 & 7)) * 8;
    const unsigned short* sV0 = VtBH + (size_t)r0 * SEQ + ((tid & 7) ^ (r0 & 7)) * 8;

    #define STAGE(nb, tt) do {                                        \
        GLL16(sK0 + (size_t)(tt) * 4096, (char*)Kl[nb] + tid * 16);   \
        GLL16(sV0 + (tt) * 64,           (char*)Vl[nb] + tid * 16);   \
    } while (0)

    int rdoff[2][4];
    #pragma unroll
    for (int s = 0; s < 2; ++s)
        #pragma unroll
        for (int f = 0; f < 4; ++f)
            rdoff[s][f] = (f * 16 + c) * 128 + ((g * 16 + s * 64) ^ sw);

    short8 qf[4][2];
    #pragma unroll
    for (int m = 0; m < 4; ++m)
        #pragma unroll
        for (int s = 0; s < 2; ++s)
            qf[m][s] = *(const short8*)(QbBH +
                         (size_t)(q0 + w * 64 + m * 16 + c) * 64 + s * 32 + g * 8);

    const short8 ones = {0x3F80, 0x3F80, 0x3F80, 0x3F80,
                         0x3F80, 0x3F80, 0x3F80, 0x3F80};   // bf16 1.0
    const f32x4 z4 = {0.f, 0.f, 0.f, 0.f};                  // shared zero C-in

    f32x4 oacc[4][4] = {};
    f32x4 lacc[4] = {};

    STAGE(0, 0);
    __syncthreads();

    #define BODY(cur, tt, PF)                                                  \
    {                                                                          \
        if (PF) STAGE(cur ^ 1, (tt) + 1);                                      \
        f32x4 st[4][4];                                                        \
        /* s = 0: C-in = shared z4 (no per-tile st zero-init) */               \
        {                                                                      \
            short8 kf[4];                                                      \
            _Pragma("unroll")                                                  \
            for (int f = 0; f < 4; ++f)                                        \
                kf[f] = *(const short8*)((char*)Kl[cur] + rdoff[0][f]);        \
            __builtin_amdgcn_s_setprio(1);                                     \
            _Pragma("unroll")                                                  \
            for (int m = 0; m < 4; ++m)                                        \
                _Pragma("unroll")                                              \
                for (int f = 0; f < 4; ++f)                                    \
                    st[m][f] = __builtin_amdgcn_mfma_f32_16x16x32_bf16(        \
                        kf[f], qf[m][0], z4, 0, 0, 0);                         \
            __builtin_amdgcn_s_setprio(0);                                     \
        }                                                                      \
        /* s = 1: accumulate */                                                \
        {                                                                      \
            short8 kf[4];                                                      \
            _Pragma("unroll")                                                  \
            for (int f = 0; f < 4; ++f)                                        \
                kf[f] = *(const short8*)((char*)Kl[cur] + rdoff[1][f]);        \
            __builtin_amdgcn_s_setprio(1);                                     \
            _Pragma("unroll")                                                  \
            for (int m = 0; m < 4; ++m)                                        \
                _Pragma("unroll")                                              \
                for (int f = 0; f < 4; ++f)                                    \
                    st[m][f] = __builtin_amdgcn_mfma_f32_16x16x32_bf16(        \
                        kf[f], qf[m][1], st[m][f], 0, 0, 0);                   \
            __builtin_amdgcn_s_setprio(0);                                     \
        }                                                                      \
        short8 pa[4][2];                                                       \
        _Pragma("unroll")                                                      \
        for (int m = 0; m < 4; ++m) {                                          \
            float p[4][4];                                                     \
            _Pragma("unroll")                                                  \
            for (int f = 0; f < 4; ++f)                                        \
                _Pragma("unroll")                                              \
                for (int r = 0; r < 4; ++r)                                    \
                    p[f][r] = exp2_fast(st[m][f][r]);                          \
            uint4 u0, u1;                                                      \
            u0.x = pkbf(p[0][0], p[0][1]); u0.y = pkbf(p[0][2], p[0][3]);      \
            u0.z = pkbf(p[1][0], p[1][1]); u0.w = pkbf(p[1][2], p[1][3]);      \
            u1.x = pkbf(p[2][0], p[2][1]); u1.y = pkbf(p[2][2], p[2][3]);      \
            u1.z = pkbf(p[3][0], p[3][1]); u1.w = pkbf(p[3][2], p[3][3]);      \
            pa[m][0] = *(short8*)&u0;                                          \
            pa[m][1] = *(short8*)&u1;                                          \
        }                                                                      \
        _Pragma("unroll")                                                      \
        for (int s = 0; s < 2; ++s) {                                          \
            short8 vb[4];                                                      \
            _Pragma("unroll")                                                  \
            for (int df = 0; df < 4; ++df)                                     \
                vb[df] = *(const short8*)((char*)Vl[cur] + rdoff[s][df]);      \
            __builtin_amdgcn_s_setprio(1);                                     \
            _Pragma("unroll")                                                  \
            for (int m = 0; m < 4; ++m) {                                      \
                lacc[m] = __builtin_amdgcn_mfma_f32_16x16x32_bf16(             \
                    ones, pa[m][s], lacc[m], 0, 0, 0);                         \
                _Pragma("unroll")                                              \
                for (int df = 0; df < 4; ++df)                                 \
                    oacc[m][df] = __builtin_amdgcn_mfma_f32_16x16x32_bf16(     \
                        vb[df], pa[m][s], oacc[m][df], 0, 0, 0);               \
            }                                                                  \
            __builtin_amdgcn_s_setprio(0);                                     \
        }                                                                      \
        __syncthreads();                                                       \
    }

    for (int t = 0; t < NT; t += 2) {
        BODY(0, t, true);
        BODY(1, t + 1, (t + 2 < NT));
    }
    #undef BODY
    #undef STAGE

    // ---- epilogue: l from lacc (col = lane's own q = c); half4 stores ----
    #pragma unroll
    for (int m = 0; m < 4; ++m) {
        const float iv = __builtin_amdgcn_rcpf(lacc[m][0]);
        const size_t t = (size_t)(b * SEQ + q0 + w * 64 + m * 16 + c);
        _Float16* orow = Of + t * 1024 + h * 64;
        #pragma unroll
        for (int df = 0; df < 4; ++df) {
            half4 o;
            o[0] = (_Float16)(oacc[m][df][0] * iv);
            o[1] = (_Float16)(oacc[m][df][1] * iv);
            o[2] = (_Float16)(oacc[m][df][2] * iv);
            o[3] = (_Float16)(oacc[m][df][3] * iv);
            *(half4*)(orow + df * 16 + 4 * g) = o;
        }
    }
}

// ---------------------------------------------------------------------------
extern "C" void kernel_launch(void* const* d_in, const int* in_sizes, int n_in,
                              void* d_out, int out_size, void* d_ws, size_t ws_size,
                              hipStream_t stream) {
    const float* x      = (const float*)d_in[0];
    const float* w_qkv  = (const float*)d_in[1];
    const float* w_proj = (const float*)d_in[2];
    const float* b_proj = (const float*)d_in[3];
    float* out = (float*)d_out;

    char* ws = (char*)d_ws;
    const size_t MB = 1024 * 1024;
    _Float16* Xf  = (_Float16*)(ws);             // 16 MB
    _Float16* Of  = Xf;                          // alias: X dead after qkv GEMM
    _Float16* Wf  = (_Float16*)(ws + 16 * MB);   // 6 MB
    _Float16* Wpf = (_Float16*)(ws + 22 * MB);   // 2 MB
    unsigned short* Qb = (unsigned short*)(ws + 24 * MB);  // 16 MB
    unsigned short* Kb = (unsigned short*)(ws + 40 * MB);  // 16 MB
    unsigned short* Vt = (unsigned short*)(ws + 56 * MB);  // 16 MB -> 72 MB total

    // 1) fp16 conversions (single launch)
    conv3<<<6144, 256, 0, stream>>>(x, Xf, w_qkv, Wf, w_proj, Wpf);

    // 2a) qkv GEMM, Q/K columns (256x128 wide-wave, swapped epilogue)
    gemm_h<0, 1><<<512, 256, 0, stream>>>(
        Xf, Wf, 1024, 3072, 16, 0, nullptr, nullptr, Qb, Kb, Vt);
    // 2b) qkv GEMM, V columns (256x128 wide-wave, unswapped epilogue)
    gemm_h<0, 0><<<256, 256, 0, stream>>>(
        Xf, Wf, 1024, 3072, 8, 2048, nullptr, nullptr, Qb, Kb, Vt);

    // 3) flash attention (64 q-rows/wave, MFMA-l, shared-zero C) -> Of
    attn_mfma<<<256, 512, 0, stream>>>(Qb, Kb, Vt, Of);

    // 4) proj GEMM (256x128 wide-wave, float4 epilogue) + bias -> out
    gemm_h<1, 1><<<256, 256, 0, stream>>>(
        Of, Wpf, 1024, 1024, 8, 0, out, b_proj, nullptr, nullptr, nullptr);
}

// Round 24
// 173.209 us; speedup vs baseline: 1.1413x; 1.0148x over previous
//
#include <hip/hip_runtime.h>
#include <stdint.h>

#define NHEAD 16
#define SEQ 2048
#define BATCH 4
#define NT (SEQ / 64)   // 32 kv tiles of 64

typedef short short8 __attribute__((ext_vector_type(8)));     // 8 bf16 (4 VGPRs)
typedef _Float16 half8 __attribute__((ext_vector_type(8)));   // 8 fp16 (4 VGPRs)
typedef _Float16 half4 __attribute__((ext_vector_type(4)));   // 4 fp16 (8B)
typedef float f32x4  __attribute__((ext_vector_type(4)));     // MFMA accumulator
typedef __bf16 bf16x2 __attribute__((ext_vector_type(2)));

typedef const __attribute__((address_space(1))) void* gas_t;
typedef __attribute__((address_space(3))) void* las_t;
#define GLL16(g, s) __builtin_amdgcn_global_load_lds((gas_t)(g), (las_t)(s), 16, 0, 0)

static __device__ __forceinline__ unsigned short f2bfn(float f) {
    union { __bf16 b; unsigned short u; } cv;
    cv.b = (__bf16)f;
    return cv.u;
}
static __device__ __forceinline__ uint32_t pkbf(float a, float b) {
    union { bf16x2 v; uint32_t u; } cv;
    cv.v[0] = (__bf16)a; cv.v[1] = (__bf16)b;
    return cv.u;
}
static __device__ __forceinline__ float exp2_fast(float x) {
#if __has_builtin(__builtin_amdgcn_exp2f)
    return __builtin_amdgcn_exp2f(x);
#else
    float r; asm("v_exp_f32 %0, %1\n\ts_nop 0" : "=v"(r) : "v"(x)); return r;
#endif
}

// ---------------------------------------------------------------------------
// Merged fp32 -> fp16 conversion for x, w_qkv, w_proj (one launch).
// ---------------------------------------------------------------------------
__global__ __launch_bounds__(256)
void conv3(const float* __restrict__ x,  _Float16* __restrict__ Xf,
           const float* __restrict__ wq, _Float16* __restrict__ Wf,
           const float* __restrict__ wp, _Float16* __restrict__ Wpf) {
    const int bid = blockIdx.x;
    const float* src;
    _Float16* dst;
    int base;
    if (bid < 4096)      { src = x;  dst = Xf;  base = bid; }
    else if (bid < 5632) { src = wq; dst = Wf;  base = bid - 4096; }
    else                 { src = wp; dst = Wpf; base = bid - 5632; }
    const int idx = (base * 256 + threadIdx.x) * 8;
    float4 v0 = *(const float4*)(src + idx);
    float4 v1 = *(const float4*)(src + idx + 4);
    half8 h;
    h[0] = (_Float16)v0.x; h[1] = (_Float16)v0.y;
    h[2] = (_Float16)v0.z; h[3] = (_Float16)v0.w;
    h[4] = (_Float16)v1.x; h[5] = (_Float16)v1.y;
    h[6] = (_Float16)v1.z; h[7] = (_Float16)v1.w;
    *(half8*)(dst + idx) = h;
}

// ---------------------------------------------------------------------------
// fp16 MFMA GEMM (r22/r23, unchanged): 256x128 macro-tile, 4 waves (2Mx2N),
// wave owns 128x64 (8x4 frags), 3-buffer depth-2 GLL16, vmcnt(6), XCD grid,
// compile-time SWP operand order + vectorized epilogues.
// ---------------------------------------------------------------------------
template<int EPI, int SWP>
__global__ __launch_bounds__(256, 2)
void gemm_h(const _Float16* __restrict__ Af, const _Float16* __restrict__ Bf,
            int K, int N, int nbx, int bnoff,
            float* __restrict__ outF, const float* __restrict__ bias,
            unsigned short* __restrict__ Qb, unsigned short* __restrict__ Kb,
            unsigned short* __restrict__ Vt) {
    __shared__ _Float16 lds[3][12288];   // [buf][ A 256x32 | B 128x32 ]

    const int tid = threadIdx.x;
    const int l = tid & 63, wv = tid >> 6;
    const int wm = wv >> 1, wn = wv & 1;       // 2 M-waves x 2 N-waves
    const int c = l & 15, g = l >> 4;

    const int id = blockIdx.x;
    const int xcd = id & 7, s = id >> 3;
    const int bpx = (gridDim.x >> 3) / nbx;    // by-rows per XCD
    const int by = xcd * bpx + s / nbx, bx = s % nbx;
    const int bm = by * 256, bn = bnoff + bx * 128;

    size_t aoff[4], boff[2];
    int ldsA[4], ldsB[2];
    #pragma unroll
    for (int u = 0; u < 4; ++u) {
        const int i = u * 256 + tid;
        const int row = i >> 2;
        const int gg = (i & 3) ^ ((row >> 1) & 3);
        aoff[u] = (size_t)(bm + row) * K + gg * 8;
        ldsA[u] = (u * 256 + wv * 64) * 8;
    }
    #pragma unroll
    for (int u = 0; u < 2; ++u) {
        const int i = u * 256 + tid;
        const int row = i >> 2;
        const int gg = (i & 3) ^ ((row >> 1) & 3);
        boff[u] = (size_t)(bn + row) * K + gg * 8;
        ldsB[u] = 8192 + (u * 256 + wv * 64) * 8;
    }

    int offA[8], offB[4];
    #pragma unroll
    for (int m = 0; m < 8; ++m) {
        const int row = wm * 128 + m * 16 + c;
        offA[m] = row * 32 + (g ^ ((row >> 1) & 3)) * 8;
    }
    #pragma unroll
    for (int n = 0; n < 4; ++n) {
        const int row = wn * 64 + n * 16 + c;
        offB[n] = 8192 + row * 32 + (g ^ ((row >> 1) & 3)) * 8;
    }

    #define GSTAGE(buf, kk) do {                              \
        _Pragma("unroll")                                     \
        for (int u = 0; u < 4; ++u)                           \
            GLL16(Af + aoff[u] + (kk), &lds[buf][ldsA[u]]);   \
        _Pragma("unroll")                                     \
        for (int u = 0; u < 2; ++u)                           \
            GLL16(Bf + boff[u] + (kk), &lds[buf][ldsB[u]]);   \
    } while (0)

    f32x4 acc[8][4] = {};
    const int NK = K >> 5;

    GSTAGE(0, 0);
    GSTAGE(1, 32);
    asm volatile("s_waitcnt vmcnt(6)" ::: "memory");
    __builtin_amdgcn_s_barrier();
    __builtin_amdgcn_sched_barrier(0);

    for (int ks = 0; ks < NK; ++ks) {
        const int cur = ks % 3;
        if (ks + 2 < NK) GSTAGE((ks + 2) % 3, (ks + 2) * 32);

        half8 a[8], b[4];
        #pragma unroll
        for (int m = 0; m < 8; ++m) a[m] = *(const half8*)&lds[cur][offA[m]];
        #pragma unroll
        for (int n = 0; n < 4; ++n) b[n] = *(const half8*)&lds[cur][offB[n]];

        __builtin_amdgcn_s_setprio(1);
        #pragma unroll
        for (int m = 0; m < 8; ++m)
            #pragma unroll
            for (int n = 0; n < 4; ++n) {
                if constexpr (SWP)
                    acc[m][n] = __builtin_amdgcn_mfma_f32_16x16x32_f16(
                        b[n], a[m], acc[m][n], 0, 0, 0);
                else
                    acc[m][n] = __builtin_amdgcn_mfma_f32_16x16x32_f16(
                        a[m], b[n], acc[m][n], 0, 0, 0);
            }
        __builtin_amdgcn_s_setprio(0);

        if (ks + 1 < NK) {
            if (ks + 2 < NK) {
                asm volatile("s_waitcnt vmcnt(6)" ::: "memory");
            } else {
                asm volatile("s_waitcnt vmcnt(0)" ::: "memory");
            }
            __builtin_amdgcn_s_barrier();
            __builtin_amdgcn_sched_barrier(0);
        }
    }
    #undef GSTAGE

    if constexpr (EPI == 0) {
        const int colbase = bn + wn * 64;                   // 64-aligned
        const int which = colbase >> 10;
        const int h = (colbase >> 6) & 15;
        if constexpr (SWP) {
            const float qs = 0.125f * 1.44269504088896340736f;
            unsigned short* plane = (which == 0) ? Qb : Kb;
            const float sc = (which == 0) ? qs : 1.0f;
            #pragma unroll
            for (int m = 0; m < 8; ++m) {
                const int t = bm + wm * 128 + m * 16 + c;
                const int bb = t >> 11, nl = t & 2047;
                unsigned short* rowp = plane +
                    ((size_t)(bb * NHEAD + h) * SEQ + nl) * 64;
                #pragma unroll
                for (int n = 0; n < 4; ++n) {
                    ushort4 o;
                    o.x = f2bfn(acc[m][n][0] * sc);
                    o.y = f2bfn(acc[m][n][1] * sc);
                    o.z = f2bfn(acc[m][n][2] * sc);
                    o.w = f2bfn(acc[m][n][3] * sc);
                    *(ushort4*)(rowp + n * 16 + 4 * g) = o;
                }
            }
        } else {
            #pragma unroll
            for (int m = 0; m < 8; ++m) {
                const int trow0 = bm + wm * 128 + m * 16 + 4 * g;
                const int bb = trow0 >> 11, nl0 = trow0 & 2047;
                #pragma unroll
                for (int n = 0; n < 4; ++n) {
                    const int d = n * 16 + c;
                    ushort4 o;
                    o.x = f2bfn(acc[m][n][0]);
                    o.y = f2bfn(acc[m][n][1]);
                    o.z = f2bfn(acc[m][n][2]);
                    o.w = f2bfn(acc[m][n][3]);
                    *(ushort4*)(Vt + ((size_t)(bb * NHEAD + h) * 64 + d) * SEQ + nl0) = o;
                }
            }
        }
    } else {
        #pragma unroll
        for (int m = 0; m < 8; ++m) {
            const int t = bm + wm * 128 + m * 16 + c;
            #pragma unroll
            for (int n = 0; n < 4; ++n) {
                const int col0 = bn + wn * 64 + n * 16 + 4 * g;
                float4 bv = *(const float4*)&bias[col0];
                float4 o;
                o.x = acc[m][n][0] + bv.x;
                o.y = acc[m][n][1] + bv.y;
                o.z = acc[m][n][2] + bv.z;
                o.w = acc[m][n][3] + bv.w;
                *(float4*)&outF[(size_t)t * N + col0] = o;
            }
        }
    }
}

// ---------------------------------------------------------------------------
// MFMA flash attention — TWO TILES PER BARRIER SPAN this round.
// 4 LDS buffer pairs (64KB). Per span: vmcnt(0)+s_barrier -> stage t+2,t+3
// -> QK(A) -> SM(A) -> QK(B) -> PV(A) -> SM(B) -> PV(B). PV(A)'s MFMAs
// issue ahead of SM(B)'s exp2 chain: VALU runs while matrix pipe drains
// (in-order issue dual-pipe overlap). Barriers 32 -> 16. Grid 256 = 1
// block/CU pins 2 waves/SIMD, so the extra register pressure is free
// (peak ~220 < 256/wave at 2 waves). Per-tile math identical to r23
// (shared-zero C, MFMA-l, tau' in-register P, swapped PV, half4 stores).
// ---------------------------------------------------------------------------
__global__ __launch_bounds__(512)
void attn_mfma(const unsigned short* __restrict__ Qb, const unsigned short* __restrict__ Kb,
               const unsigned short* __restrict__ Vt, _Float16* __restrict__ Of) {
    __shared__ unsigned short Kl[4][4096];   // [buf][64 row][64 d], rows = tau'-permuted kv
    __shared__ unsigned short Vl[4][4096];   // [buf][64 d][64 kv], natural kv

    const int tid = threadIdx.x;
    const int l = tid & 63, w = tid >> 6;
    const int g = l >> 4, c = l & 15;
    const int sw = (c & 7) << 4;

    const int blk = blockIdx.x;
    const int xcd = blk & 7, s0 = blk >> 3;        // s0 = 0..31
    const int bh = xcd * 8 + (s0 >> 2);
    const int b = bh >> 4, h = bh & 15;
    const int q0 = (s0 & 3) * 512;

    const unsigned short* QbBH = Qb + (size_t)bh * SEQ * 64;
    const unsigned short* KbBH = Kb + (size_t)bh * SEQ * 64;
    const unsigned short* VtBH = Vt + (size_t)bh * 64 * SEQ;

    const int r0 = tid >> 3;
    const int tau0 = (r0 & 32) | ((r0 & 12) << 1) | ((r0 & 16) >> 2) | (r0 & 3);
    const unsigned short* sK0 = KbBH + (size_t)tau0 * 64 + ((tid & 7) ^ (r0 & 7)) * 8;
    const unsigned short* sV0 = VtBH + (size_t)r0 * SEQ + ((tid & 7) ^ (r0 & 7)) * 8;

    #define STAGE(nb, tt) do {                                        \
        GLL16(sK0 + (size_t)(tt) * 4096, (char*)Kl[nb] + tid * 16);   \
        GLL16(sV0 + (tt) * 64,           (char*)Vl[nb] + tid * 16);   \
    } while (0)

    int rdoff[2][4];
    #pragma unroll
    for (int s = 0; s < 2; ++s)
        #pragma unroll
        for (int f = 0; f < 4; ++f)
            rdoff[s][f] = (f * 16 + c) * 128 + ((g * 16 + s * 64) ^ sw);

    short8 qf[4][2];
    #pragma unroll
    for (int m = 0; m < 4; ++m)
        #pragma unroll
        for (int s = 0; s < 2; ++s)
            qf[m][s] = *(const short8*)(QbBH +
                         (size_t)(q0 + w * 64 + m * 16 + c) * 64 + s * 32 + g * 8);

    const short8 ones = {0x3F80, 0x3F80, 0x3F80, 0x3F80,
                         0x3F80, 0x3F80, 0x3F80, 0x3F80};   // bf16 1.0
    const f32x4 z4 = {0.f, 0.f, 0.f, 0.f};                  // shared zero C-in

    f32x4 oacc[4][4] = {};
    f32x4 lacc[4] = {};

    STAGE(0, 0);
    STAGE(1, 1);

    // QK for buffer bb into st
    #define QK(bb, st)                                                         \
    {                                                                          \
        short8 kf[4];                                                          \
        _Pragma("unroll")                                                      \
        for (int f = 0; f < 4; ++f)                                            \
            kf[f] = *(const short8*)((char*)Kl[bb] + rdoff[0][f]);             \
        __builtin_amdgcn_s_setprio(1);                                         \
        _Pragma("unroll")                                                      \
        for (int m = 0; m < 4; ++m)                                            \
            _Pragma("unroll")                                                  \
            for (int f = 0; f < 4; ++f)                                        \
                st[m][f] = __builtin_amdgcn_mfma_f32_16x16x32_bf16(            \
                    kf[f], qf[m][0], z4, 0, 0, 0);                             \
        __builtin_amdgcn_s_setprio(0);                                         \
        _Pragma("unroll")                                                      \
        for (int f = 0; f < 4; ++f)                                            \
            kf[f] = *(const short8*)((char*)Kl[bb] + rdoff[1][f]);             \
        __builtin_amdgcn_s_setprio(1);                                         \
        _Pragma("unroll")                                                      \
        for (int m = 0; m < 4; ++m)                                            \
            _Pragma("unroll")                                                  \
            for (int f = 0; f < 4; ++f)                                        \
                st[m][f] = __builtin_amdgcn_mfma_f32_16x16x32_bf16(            \
                    kf[f], qf[m][1], st[m][f], 0, 0, 0);                       \
        __builtin_amdgcn_s_setprio(0);                                         \
    }

    // softmax: st -> pa (exp2 + pack; l handled by MFMA-ones in PV)
    #define SM(st, pa)                                                         \
    _Pragma("unroll")                                                          \
    for (int m = 0; m < 4; ++m) {                                              \
        float p[4][4];                                                         \
        _Pragma("unroll")                                                      \
        for (int f = 0; f < 4; ++f)                                            \
            _Pragma("unroll")                                                  \
            for (int r = 0; r < 4; ++r)                                        \
                p[f][r] = exp2_fast(st[m][f][r]);                              \
        uint4 u0, u1;                                                          \
        u0.x = pkbf(p[0][0], p[0][1]); u0.y = pkbf(p[0][2], p[0][3]);          \
        u0.z = pkbf(p[1][0], p[1][1]); u0.w = pkbf(p[1][2], p[1][3]);          \
        u1.x = pkbf(p[2][0], p[2][1]); u1.y = pkbf(p[2][2], p[2][3]);          \
        u1.z = pkbf(p[3][0], p[3][1]); u1.w = pkbf(p[3][2], p[3][3]);          \
        pa[m][0] = *(short8*)&u0;                                              \
        pa[m][1] = *(short8*)&u1;                                              \
    }

    // PV + lacc for buffer bb with fragments pa
    #define PV(bb, pa)                                                         \
    _Pragma("unroll")                                                          \
    for (int s = 0; s < 2; ++s) {                                              \
        short8 vb[4];                                                          \
        _Pragma("unroll")                                                      \
        for (int df = 0; df < 4; ++df)                                         \
            vb[df] = *(const short8*)((char*)Vl[bb] + rdoff[s][df]);           \
        __builtin_amdgcn_s_setprio(1);                                         \
        _Pragma("unroll")                                                      \
        for (int m = 0; m < 4; ++m) {                                          \
            lacc[m] = __builtin_amdgcn_mfma_f32_16x16x32_bf16(                 \
                ones, pa[m][s], lacc[m], 0, 0, 0);                             \
            _Pragma("unroll")                                                  \
            for (int df = 0; df < 4; ++df)                                     \
                oacc[m][df] = __builtin_amdgcn_mfma_f32_16x16x32_bf16(         \
                    vb[df], pa[m][s], oacc[m][df], 0, 0, 0);                   \
        }                                                                      \
        __builtin_amdgcn_s_setprio(0);                                         \
    }

    // two tiles per barrier span; stage the next pair right after the barrier
    #define BODY2(bA, bB, tt, PF)                                              \
    {                                                                          \
        asm volatile("s_waitcnt vmcnt(0)" ::: "memory");                       \
        __builtin_amdgcn_s_barrier();                                          \
        __builtin_amdgcn_sched_barrier(0);                                     \
        if (PF) { STAGE(bA ^ 2, (tt) + 2); STAGE(bB ^ 2, (tt) + 3); }          \
        f32x4 st[4][4];                                                        \
        short8 paA[4][2], paB[4][2];                                           \
        QK(bA, st)                                                             \
        SM(st, paA)                                                            \
        QK(bB, st)                                                             \
        PV(bA, paA)                                                            \
        SM(st, paB)                                                            \
        PV(bB, paB)                                                            \
    }

    for (int t = 0; t < NT; t += 4) {
        BODY2(0, 1, t,     true);
        BODY2(2, 3, t + 2, (t + 4 < NT));
    }
    #undef BODY2
    #undef QK
    #undef SM
    #undef PV
    #undef STAGE

    // ---- epilogue: l from lacc (col = lane's own q = c); half4 stores ----
    #pragma unroll
    for (int m = 0; m < 4; ++m) {
        const float iv = __builtin_amdgcn_rcpf(lacc[m][0]);
        const size_t t = (size_t)(b * SEQ + q0 + w * 64 + m * 16 + c);
        _Float16* orow = Of + t * 1024 + h * 64;
        #pragma unroll
        for (int df = 0; df < 4; ++df) {
            half4 o;
            o[0] = (_Float16)(oacc[m][df][0] * iv);
            o[1] = (_Float16)(oacc[m][df][1] * iv);
            o[2] = (_Float16)(oacc[m][df][2] * iv);
            o[3] = (_Float16)(oacc[m][df][3] * iv);
            *(half4*)(orow + df * 16 + 4 * g) = o;
        }
    }
}

// ---------------------------------------------------------------------------
extern "C" void kernel_launch(void* const* d_in, const int* in_sizes, int n_in,
                              void* d_out, int out_size, void* d_ws, size_t ws_size,
                              hipStream_t stream) {
    const float* x      = (const float*)d_in[0];
    const float* w_qkv  = (const float*)d_in[1];
    const float* w_proj = (const float*)d_in[2];
    const float* b_proj = (const float*)d_in[3];
    float* out = (float*)d_out;

    char* ws = (char*)d_ws;
    const size_t MB = 1024 * 1024;
    _Float16* Xf  = (_Float16*)(ws);             // 16 MB
    _Float16* Of  = Xf;                          // alias: X dead after qkv GEMM
    _Float16* Wf  = (_Float16*)(ws + 16 * MB);   // 6 MB
    _Float16* Wpf = (_Float16*)(ws + 22 * MB);   // 2 MB
    unsigned short* Qb = (unsigned short*)(ws + 24 * MB);  // 16 MB
    unsigned short* Kb = (unsigned short*)(ws + 40 * MB);  // 16 MB
    unsigned short* Vt = (unsigned short*)(ws + 56 * MB);  // 16 MB -> 72 MB total

    // 1) fp16 conversions (single launch)
    conv3<<<6144, 256, 0, stream>>>(x, Xf, w_qkv, Wf, w_proj, Wpf);

    // 2a) qkv GEMM, Q/K columns (256x128 wide-wave, swapped epilogue)
    gemm_h<0, 1><<<512, 256, 0, stream>>>(
        Xf, Wf, 1024, 3072, 16, 0, nullptr, nullptr, Qb, Kb, Vt);
    // 2b) qkv GEMM, V columns (256x128 wide-wave, unswapped epilogue)
    gemm_h<0, 0><<<256, 256, 0, stream>>>(
        Xf, Wf, 1024, 3072, 8, 2048, nullptr, nullptr, Qb, Kb, Vt);

    // 3) flash attention (2 tiles/barrier, 4-buffer, MFMA-l) -> Of
    attn_mfma<<<256, 512, 0, stream>>>(Qb, Kb, Vt, Of);

    // 4) proj GEMM (256x128 wide-wave, float4 epilogue) + bias -> out
    gemm_h<1, 1><<<256, 256, 0, stream>>>(
        Of, Wpf, 1024, 1024, 8, 0, out, b_proj, nullptr, nullptr, nullptr);
}